// Round 4
// baseline (445.120 us; speedup 1.0000x reference)
//
#include <hip/hip_runtime.h>
#include <hip/hip_bf16.h>

// Model_3315714753203: B=4,S=2048,I=512,D=512,H=8,HD=64,P=720.
// Reference is fp32; harness dtype ambiguous -> runtime probe decides fp32 vs
// bf16 decode of d_in, everything converted to internal bf16, output stored
// per-flag. Pipeline: probe -> convert(+W transpose) -> GEMM q,k,vT -> flash
// attention -> GEMM up -> GEMM out.
//
// Workspace layout (bf16 element offsets; total 19304448 el = 38.6MB):
//   0        flag (int)
//   64       bqc(512) 576 bkc(512) 1088 bvc(512) 1600 btc(720) 2320 boc(512)
//   4096     WqT [8][64][512]
//   266240   WkT
//   528384   WvT
//   790528   Wtc [720][2048]
//   2265088  Woc [512][512]
//   2527232  Xc  [4][2048][512]   (dead after QKV gemms) -> cT [4][512][2048]
//   6721536  q   [8*4][2048][64]  (dead after flash)     -> up [4][720][512]
//   10915840 kk  [8*4][2048][64]
//   15110144 vT  [8*4][64][2048]

typedef short bf16x8 __attribute__((ext_vector_type(8)));
typedef float f32x4 __attribute__((ext_vector_type(4)));
typedef const __attribute__((address_space(1))) void* gptr_t;
typedef __attribute__((address_space(3))) void* sptr_t;

__device__ __forceinline__ f32x4 mfma16(bf16x8 a, bf16x8 b, f32x4 c) {
    return __builtin_amdgcn_mfma_f32_16x16x32_bf16(a, b, c, 0, 0, 0);
}
__device__ __forceinline__ void async16(const void* g, void* l) {
    __builtin_amdgcn_global_load_lds((gptr_t)g, (sptr_t)l, 16, 0, 0);
}

// ---------------- dtype probe: are the raw input words fp32?
// X ~ N(0,1): stored fp32 -> u32 exponent field in [100,145] for ~97% of
// words; stored bf16 pairs -> that field is mantissa garbage (~16% hit rate).
__global__ void probe_dtype(const unsigned* __restrict__ x, int* __restrict__ flag) {
    __shared__ int cnt[256];
    int c = 0;
    for (int i = threadIdx.x; i < 1024; i += 256) {
        unsigned e = (x[i] >> 23) & 0xffu;
        c += (e >= 100u && e <= 145u) ? 1 : 0;
    }
    cnt[threadIdx.x] = c;
    __syncthreads();
    for (int s = 128; s > 0; s >>= 1) {
        if (threadIdx.x < s) cnt[threadIdx.x] += cnt[threadIdx.x + s];
        __syncthreads();
    }
    if (threadIdx.x == 0) *flag = (cnt[0] >= 512) ? 1 : 0;
}

// ---------------- convert all inputs to internal bf16 (mode1 = HID->HDI transpose)
struct CDesc { const void* s; __hip_bfloat16* d; int n; int mode; };
struct CTab  { CDesc t[11]; };

__global__ void convert_all(CTab tab, const int* __restrict__ flag) {
    CDesc de = tab.t[blockIdx.y];
    const int isF32 = *flag;
    for (int i = blockIdx.x * 256 + threadIdx.x; i < de.n; i += gridDim.x * 256) {
        int si = i;
        if (de.mode) {  // dst [h][d][i512]: i=(h*64+d)*512+ii  src [h][i512][d]
            int ii = i & 511, d = (i >> 9) & 63, h = i >> 15;
            si = (h * 512 + ii) * 64 + d;
        }
        float v = isF32 ? ((const float*)de.s)[si]
                        : (float)((const __hip_bfloat16*)de.s)[si];
        de.d[i] = __float2bfloat16(v);
    }
}

// ---------------- generic MFMA GEMM: C[M,N] = A[M,K] * B[N,K]^T (+biasM/biasN)
// batch z = z1*Z0+z0; element strides. outF32flag: nullptr -> bf16 C, else
// runtime flag selects fp32/bf16 stores (for d_out whose dtype is probed).
template<int BM, int BN>
__global__ __launch_bounds__(256, 2) void gemm_bt(
    const __hip_bfloat16* __restrict__ A,
    const __hip_bfloat16* __restrict__ B,
    void* __restrict__ C,
    int M, int N, int K, int lda, int ldb, int ldc,
    long sA1, long sA0, long sB1, long sB0, long sC1, long sC0,
    const __hip_bfloat16* __restrict__ biasM, long sbM1,
    const __hip_bfloat16* __restrict__ biasN, long sbN1,
    int Z0, const int* __restrict__ outF32flag)
{
    constexpr int BK = 64;
    const int z = blockIdx.z;
    const int z1 = z / Z0, z0 = z - z1 * Z0;
    A += (size_t)z1 * sA1 + (size_t)z0 * sA0;
    B += (size_t)z1 * sB1 + (size_t)z0 * sB0;
    const size_t cbase = (size_t)z1 * sC1 + (size_t)z0 * sC0;
    if (biasM) biasM += (size_t)z1 * sbM1;
    if (biasN) biasN += (size_t)z1 * sbN1;
    const int outF32 = outF32flag ? *outF32flag : 0;

    __shared__ __align__(16) __hip_bfloat16 lA[BM * BK];
    __shared__ __align__(16) __hip_bfloat16 lB[BN * BK];

    const int tid  = threadIdx.x;
    const int lane = tid & 63;
    const int wave = tid >> 6;
    const int m0 = blockIdx.y * BM;
    const int n0 = blockIdx.x * BN;
    constexpr int WM = BM / 2, WN = BN / 2, FM = WM / 16, FN = WN / 16;
    const int wm = (wave >> 1) * WM, wn = (wave & 1) * WN;
    const int lc = lane & 15, lg = lane >> 4;

    f32x4 acc[FM][FN] = {};

    constexpr int CA = BM * 8 / 256;
    constexpr int CB = BN * 8 / 256;

    for (int k0 = 0; k0 < K; k0 += BK) {
        #pragma unroll
        for (int j = 0; j < CA; ++j) {
            int ch = j * 256 + tid;
            int m = ch >> 3, kc = ch & 7;
            int mg = m0 + m; if (mg > M - 1) mg = M - 1;
            async16(&A[(size_t)mg * lda + k0 + kc * 8], &lA[ch * 8]);
        }
        #pragma unroll
        for (int j = 0; j < CB; ++j) {
            int ch = j * 256 + tid;
            int n = ch >> 3, kc = ch & 7;
            int ng = n0 + n; if (ng > N - 1) ng = N - 1;
            async16(&B[(size_t)ng * ldb + k0 + kc * 8], &lB[ch * 8]);
        }
        __syncthreads();
        #pragma unroll
        for (int ks = 0; ks < BK; ks += 32) {
            bf16x8 af[FM], bfr[FN];
            #pragma unroll
            for (int i = 0; i < FM; ++i)
                af[i] = *(const bf16x8*)&lA[(wm + i * 16 + lc) * BK + ks + lg * 8];
            #pragma unroll
            for (int j = 0; j < FN; ++j)
                bfr[j] = *(const bf16x8*)&lB[(wn + j * 16 + lc) * BK + ks + lg * 8];
            #pragma unroll
            for (int i = 0; i < FM; ++i)
                #pragma unroll
                for (int j = 0; j < FN; ++j)
                    acc[i][j] = mfma16(af[i], bfr[j], acc[i][j]);
        }
        __syncthreads();
    }

    #pragma unroll
    for (int i = 0; i < FM; ++i) {
        int rbase = m0 + wm + i * 16 + lg * 4;
        #pragma unroll
        for (int j = 0; j < FN; ++j) {
            int col = n0 + wn + j * 16 + lc;
            if (col >= N) continue;
            float bn = biasN ? (float)biasN[col] : 0.0f;
            #pragma unroll
            for (int r = 0; r < 4; ++r) {
                int row = rbase + r;
                if (row < M) {
                    float v = acc[i][j][r] + bn;
                    if (biasM) v += (float)biasM[row];
                    size_t idx = cbase + (size_t)row * ldc + col;
                    if (outF32) ((float*)C)[idx] = v;
                    else ((__hip_bfloat16*)C)[idx] = __float2bfloat16(v);
                }
            }
        }
    }
}

// ---------------- flash attention
// q,k: [H*B][S][64]; vT: [H*B][64][S]; out cT: [B][512][S] (combined^T)
__global__ __launch_bounds__(256, 2) void flash_attn(
    const __hip_bfloat16* __restrict__ q,
    const __hip_bfloat16* __restrict__ k,
    const __hip_bfloat16* __restrict__ vT,
    __hip_bfloat16* __restrict__ cT)
{
    const int S = 2048;
    const int h = blockIdx.y >> 2, b = blockIdx.y & 3;
    const int tid = threadIdx.x, lane = tid & 63, wave = tid >> 6;
    const int lc = lane & 15, lg = lane >> 4;
    const int s0 = blockIdx.x * 64 + wave * 16;

    const __hip_bfloat16* qb = q  + (size_t)(h * 4 + b) * S * 64;
    const __hip_bfloat16* kb = k  + (size_t)(h * 4 + b) * S * 64;
    const __hip_bfloat16* vb = vT + (size_t)(h * 4 + b) * 64 * S;

    __shared__ __align__(16) __hip_bfloat16 lP[4][16 * 32];
    __shared__ __align__(16) __hip_bfloat16 lT[64 * 64];

    bf16x8 aq0 = *(const bf16x8*)&qb[(size_t)(s0 + lc) * 64 + lg * 8];
    bf16x8 aq1 = *(const bf16x8*)&qb[(size_t)(s0 + lc) * 64 + 32 + lg * 8];

    f32x4 O[4] = {};
    float mr[4], lr[4];
    #pragma unroll
    for (int r = 0; r < 4; ++r) { mr[r] = -1e30f; lr[r] = 0.0f; }

    const float sc_fac = 1.0f / 64.0f;   // reference divides by head_size, not sqrt
    for (int t0 = 0; t0 < S; t0 += 32) {
        f32x4 sc[2];
        #pragma unroll
        for (int nt = 0; nt < 2; ++nt) {
            const __hip_bfloat16* kr = &kb[(size_t)(t0 + nt * 16 + lc) * 64];
            bf16x8 b0 = *(const bf16x8*)&kr[lg * 8];
            bf16x8 b1 = *(const bf16x8*)&kr[32 + lg * 8];
            f32x4 s = {};
            s = mfma16(aq0, b0, s);
            s = mfma16(aq1, b1, s);
            sc[nt] = s * sc_fac;
        }
        float nm[4], al[4];
        #pragma unroll
        for (int r = 0; r < 4; ++r) {
            float mx = fmaxf(sc[0][r], sc[1][r]);
            mx = fmaxf(mx, __shfl_xor(mx, 1));
            mx = fmaxf(mx, __shfl_xor(mx, 2));
            mx = fmaxf(mx, __shfl_xor(mx, 4));
            mx = fmaxf(mx, __shfl_xor(mx, 8));
            nm[r] = fmaxf(mr[r], mx);
        }
        #pragma unroll
        for (int nt = 0; nt < 2; ++nt)
            #pragma unroll
            for (int r = 0; r < 4; ++r)
                sc[nt][r] = __expf(sc[nt][r] - nm[r]);
        #pragma unroll
        for (int r = 0; r < 4; ++r) {
            float sm = sc[0][r] + sc[1][r];
            sm += __shfl_xor(sm, 1);
            sm += __shfl_xor(sm, 2);
            sm += __shfl_xor(sm, 4);
            sm += __shfl_xor(sm, 8);
            al[r] = __expf(mr[r] - nm[r]);
            lr[r] = lr[r] * al[r] + sm;
            mr[r] = nm[r];
        }
        #pragma unroll
        for (int dt = 0; dt < 4; ++dt)
            #pragma unroll
            for (int r = 0; r < 4; ++r)
                O[dt][r] *= al[r];
        // P: C-layout -> LDS -> A-layout (per-wave round-trip; fenced)
        __hip_bfloat16* wp = lP[wave];
        #pragma unroll
        for (int nt = 0; nt < 2; ++nt)
            #pragma unroll
            for (int r = 0; r < 4; ++r)
                wp[(lg * 4 + r) * 32 + nt * 16 + lc] = __float2bfloat16(sc[nt][r]);
        asm volatile("s_waitcnt lgkmcnt(0)" ::: "memory");
        bf16x8 pa = *(const bf16x8*)&wp[lc * 32 + lg * 8];
        asm volatile("" ::: "memory");
        #pragma unroll
        for (int dt = 0; dt < 4; ++dt) {
            bf16x8 vf = *(const bf16x8*)&vb[(size_t)(dt * 16 + lc) * S + t0 + lg * 8];
            O[dt] = mfma16(pa, vf, O[dt]);
        }
    }
    #pragma unroll
    for (int r = 0; r < 4; ++r) lr[r] = 1.0f / lr[r];
    #pragma unroll
    for (int dt = 0; dt < 4; ++dt)
        #pragma unroll
        for (int r = 0; r < 4; ++r)
            lT[(dt * 16 + lc) * 64 + wave * 16 + lg * 4 + r] = __float2bfloat16(O[dt][r] * lr[r]);
    __syncthreads();
    int row = tid >> 2, c8 = (tid & 3) * 8;
    size_t off = ((size_t)b * 512 + h * 64 + row) * S + blockIdx.x * 64;
    *(bf16x8*)&cT[off + c8]      = *(const bf16x8*)&lT[row * 64 + c8];
    *(bf16x8*)&cT[off + 32 + c8] = *(const bf16x8*)&lT[row * 64 + 32 + c8];
}

extern "C" void kernel_launch(void* const* d_in, const int* in_sizes, int n_in,
                              void* d_out, int out_size, void* d_ws, size_t ws_size,
                              hipStream_t stream) {
    using bf = __hip_bfloat16;
    bf* ws = (bf*)d_ws;
    int* flag = (int*)d_ws;
    bf* bqc = ws + 64;
    bf* bkc = ws + 576;
    bf* bvc = ws + 1088;
    bf* btc = ws + 1600;
    bf* boc = ws + 2320;
    bf* WqT = ws + 4096;       // [8][64][512]
    bf* WkT = ws + 266240;
    bf* WvT = ws + 528384;
    bf* Wtc = ws + 790528;     // [720][2048]
    bf* Woc = ws + 2265088;    // [512][512]
    bf* Xc  = ws + 2527232;    // [4][2048][512], dead after QKV gemms
    bf* cT  = ws + 2527232;    // [4][512][2048], overlays Xc
    bf* q   = ws + 6721536;    // [32][2048][64], dead after flash
    bf* up  = ws + 6721536;    // [4][720][512], overlays q
    bf* kk  = ws + 10915840;   // [32][2048][64]
    bf* vT  = ws + 15110144;   // [32][64][2048]

    probe_dtype<<<dim3(1), 256, 0, stream>>>((const unsigned*)d_in[0], flag);

    CTab tab;
    tab.t[0]  = { d_in[0],  Xc,  4194304, 0 };
    tab.t[1]  = { d_in[1],  WqT, 262144,  1 };
    tab.t[2]  = { d_in[2],  bqc, 512,     0 };
    tab.t[3]  = { d_in[3],  WkT, 262144,  1 };
    tab.t[4]  = { d_in[4],  bkc, 512,     0 };
    tab.t[5]  = { d_in[5],  WvT, 262144,  1 };
    tab.t[6]  = { d_in[6],  bvc, 512,     0 };
    tab.t[7]  = { d_in[7],  Wtc, 1474560, 0 };
    tab.t[8]  = { d_in[8],  btc, 720,     0 };
    tab.t[9]  = { d_in[9],  Woc, 262144,  0 };
    tab.t[10] = { d_in[10], boc, 512,     0 };
    convert_all<<<dim3(2048, 11), 256, 0, stream>>>(tab, flag);

    // q[h] = Xc[8192,512] * WqT[h][64,512]^T + bq[h]   (z1 = h)
    gemm_bt<128, 64><<<dim3(1, 64, 8), 256, 0, stream>>>(
        Xc, WqT, q, 8192, 64, 512, 512, 512, 64,
        0, 0, 32768, 0, 524288, 0, nullptr, 0, bqc, 64, 1, nullptr);
    gemm_bt<128, 64><<<dim3(1, 64, 8), 256, 0, stream>>>(
        Xc, WkT, kk, 8192, 64, 512, 512, 512, 64,
        0, 0, 32768, 0, 524288, 0, nullptr, 0, bkc, 64, 1, nullptr);

    // vT[h,b] = WvT[h][64,512] * Xc[b][2048,512]^T + bv[h] (per-row)  (z1=h, z0=b)
    gemm_bt<64, 128><<<dim3(16, 1, 32), 256, 0, stream>>>(
        WvT, Xc, vT, 64, 2048, 512, 512, 512, 2048,
        32768, 0, 0, 1048576, 524288, 131072, bvc, 64, nullptr, 0, 4, nullptr);

    flash_attn<<<dim3(32, 32), 256, 0, stream>>>(q, kk, vT, cT);

    // up[b] = Wt[720,2048] * cT[b][512,2048]^T + bt (per-row)   (z1 = b)
    gemm_bt<128, 128><<<dim3(4, 6, 4), 256, 0, stream>>>(
        Wtc, cT, up, 720, 512, 2048, 2048, 2048, 512,
        0, 0, 1048576, 0, 368640, 0, btc, 0, nullptr, 0, 1, nullptr);

    // out = up[2880,512] * Woc[512,512]^T + bo (per-col); dtype per probe flag
    gemm_bt<128, 128><<<dim3(4, 23, 1), 256, 0, stream>>>(
        up, Woc, d_out, 2880, 512, 512, 512, 512, 512,
        0, 0, 0, 0, 0, 0, nullptr, 0, boc, 0, 1, flag);
}

// Round 5
// 441.242 us; speedup vs baseline: 1.0088x; 1.0088x over previous
//
#include <hip/hip_runtime.h>
#include <hip/hip_bf16.h>

// Model_3315714753203: B=4,S=2048,I=512,D=512,H=8,HD=64,P=720.
// fp32 inputs (probed) -> internal bf16. probe -> convert(+W transpose) ->
// GEMM q,k,vT -> flash attention (fixed-max softmax, deferred row-sum) ->
// GEMM up -> GEMM out.

typedef short bf16x8 __attribute__((ext_vector_type(8)));
typedef float f32x4 __attribute__((ext_vector_type(4)));
typedef const __attribute__((address_space(1))) void* gptr_t;
typedef __attribute__((address_space(3))) void* sptr_t;

__device__ __forceinline__ f32x4 mfma16(bf16x8 a, bf16x8 b, f32x4 c) {
    return __builtin_amdgcn_mfma_f32_16x16x32_bf16(a, b, c, 0, 0, 0);
}
__device__ __forceinline__ void async16(const void* g, void* l) {
    __builtin_amdgcn_global_load_lds((gptr_t)g, (sptr_t)l, 16, 0, 0);
}

// ---------------- dtype probe (kept: decides fp32 vs bf16 decode at runtime)
__global__ void probe_dtype(const unsigned* __restrict__ x, int* __restrict__ flag) {
    __shared__ int cnt[256];
    int c = 0;
    for (int i = threadIdx.x; i < 1024; i += 256) {
        unsigned e = (x[i] >> 23) & 0xffu;
        c += (e >= 100u && e <= 145u) ? 1 : 0;
    }
    cnt[threadIdx.x] = c;
    __syncthreads();
    for (int s = 128; s > 0; s >>= 1) {
        if (threadIdx.x < s) cnt[threadIdx.x] += cnt[threadIdx.x + s];
        __syncthreads();
    }
    if (threadIdx.x == 0) *flag = (cnt[0] >= 512) ? 1 : 0;
}

// ---------------- convert all inputs to internal bf16 (mode1 = HID->HDI transpose)
struct CDesc { const void* s; __hip_bfloat16* d; int n; int mode; };
struct CTab  { CDesc t[11]; };

__global__ void convert_all(CTab tab, const int* __restrict__ flag) {
    CDesc de = tab.t[blockIdx.y];
    const int isF32 = *flag;
    for (int i = blockIdx.x * 256 + threadIdx.x; i < de.n; i += gridDim.x * 256) {
        int si = i;
        if (de.mode) {  // dst [h][d][i512]: i=(h*64+d)*512+ii  src [h][i512][d]
            int ii = i & 511, d = (i >> 9) & 63, h = i >> 15;
            si = (h * 512 + ii) * 64 + d;
        }
        float v = isF32 ? ((const float*)de.s)[si]
                        : (float)((const __hip_bfloat16*)de.s)[si];
        de.d[i] = __float2bfloat16(v);
    }
}

// ---------------- generic MFMA GEMM: C[M,N] = (A[M,K] * B[N,K]^T + bias) * cscale
template<int BM, int BN>
__global__ __launch_bounds__(256, 2) void gemm_bt(
    const __hip_bfloat16* __restrict__ A,
    const __hip_bfloat16* __restrict__ B,
    void* __restrict__ C,
    int M, int N, int K, int lda, int ldb, int ldc,
    long sA1, long sA0, long sB1, long sB0, long sC1, long sC0,
    const __hip_bfloat16* __restrict__ biasM, long sbM1,
    const __hip_bfloat16* __restrict__ biasN, long sbN1,
    int Z0, const int* __restrict__ outF32flag, float cscale)
{
    constexpr int BK = 64;
    const int z = blockIdx.z;
    const int z1 = z / Z0, z0 = z - z1 * Z0;
    A += (size_t)z1 * sA1 + (size_t)z0 * sA0;
    B += (size_t)z1 * sB1 + (size_t)z0 * sB0;
    const size_t cbase = (size_t)z1 * sC1 + (size_t)z0 * sC0;
    if (biasM) biasM += (size_t)z1 * sbM1;
    if (biasN) biasN += (size_t)z1 * sbN1;
    const int outF32 = outF32flag ? *outF32flag : 0;

    __shared__ __align__(16) __hip_bfloat16 lA[BM * BK];
    __shared__ __align__(16) __hip_bfloat16 lB[BN * BK];

    const int tid  = threadIdx.x;
    const int lane = tid & 63;
    const int wave = tid >> 6;
    const int m0 = blockIdx.y * BM;
    const int n0 = blockIdx.x * BN;
    constexpr int WM = BM / 2, WN = BN / 2, FM = WM / 16, FN = WN / 16;
    const int wm = (wave >> 1) * WM, wn = (wave & 1) * WN;
    const int lc = lane & 15, lg = lane >> 4;

    f32x4 acc[FM][FN] = {};

    constexpr int CA = BM * 8 / 256;
    constexpr int CB = BN * 8 / 256;

    for (int k0 = 0; k0 < K; k0 += BK) {
        #pragma unroll
        for (int j = 0; j < CA; ++j) {
            int ch = j * 256 + tid;
            int m = ch >> 3, kc = ch & 7;
            int mg = m0 + m; if (mg > M - 1) mg = M - 1;
            async16(&A[(size_t)mg * lda + k0 + kc * 8], &lA[ch * 8]);
        }
        #pragma unroll
        for (int j = 0; j < CB; ++j) {
            int ch = j * 256 + tid;
            int n = ch >> 3, kc = ch & 7;
            int ng = n0 + n; if (ng > N - 1) ng = N - 1;
            async16(&B[(size_t)ng * ldb + k0 + kc * 8], &lB[ch * 8]);
        }
        __syncthreads();
        #pragma unroll
        for (int ks = 0; ks < BK; ks += 32) {
            bf16x8 af[FM], bfr[FN];
            #pragma unroll
            for (int i = 0; i < FM; ++i)
                af[i] = *(const bf16x8*)&lA[(wm + i * 16 + lc) * BK + ks + lg * 8];
            #pragma unroll
            for (int j = 0; j < FN; ++j)
                bfr[j] = *(const bf16x8*)&lB[(wn + j * 16 + lc) * BK + ks + lg * 8];
            #pragma unroll
            for (int i = 0; i < FM; ++i)
                #pragma unroll
                for (int j = 0; j < FN; ++j)
                    acc[i][j] = mfma16(af[i], bfr[j], acc[i][j]);
        }
        __syncthreads();
    }

    #pragma unroll
    for (int i = 0; i < FM; ++i) {
        int rbase = m0 + wm + i * 16 + lg * 4;
        #pragma unroll
        for (int j = 0; j < FN; ++j) {
            int col = n0 + wn + j * 16 + lc;
            if (col >= N) continue;
            float bn = biasN ? (float)biasN[col] : 0.0f;
            #pragma unroll
            for (int r = 0; r < 4; ++r) {
                int row = rbase + r;
                if (row < M) {
                    float v = acc[i][j][r] + bn;
                    if (biasM) v += (float)biasM[row];
                    v *= cscale;
                    size_t idx = cbase + (size_t)row * ldc + col;
                    if (outF32) ((float*)C)[idx] = v;
                    else ((__hip_bfloat16*)C)[idx] = __float2bfloat16(v);
                }
            }
        }
    }
}

// ---------------- flash attention v2
// q is PRE-SCALED by log2(e)/64 in its GEMM -> softmax numerator = 2^(q.k).
// Fixed max (scores tiny, exp can't overflow), row-sum deferred to epilogue:
// NO cross-lane ops in the loop. 64 keys/iter = 16 MFMAs per LDS fence.
// q,k: [H*B][S][64]; vT: [H*B][64][S]; out cT: [B][512][S] (combined^T)
__global__ __launch_bounds__(256, 2) void flash_attn(
    const __hip_bfloat16* __restrict__ q,
    const __hip_bfloat16* __restrict__ k,
    const __hip_bfloat16* __restrict__ vT,
    __hip_bfloat16* __restrict__ cT)
{
    const int S = 2048;
    const int h = blockIdx.y >> 2, b = blockIdx.y & 3;
    const int tid = threadIdx.x, lane = tid & 63, wave = tid >> 6;
    const int lc = lane & 15, lg = lane >> 4;
    const int s0 = blockIdx.x * 64 + wave * 16;

    const __hip_bfloat16* qb = q  + (size_t)(h * 4 + b) * S * 64;
    const __hip_bfloat16* kb = k  + (size_t)(h * 4 + b) * S * 64;
    const __hip_bfloat16* vb = vT + (size_t)(h * 4 + b) * 64 * S;

    // loop: per-wave P tile [16 q][72] (stride 72: rows 144B, 16B-aligned).
    // epilogue: reused as [64 d][72 s] transpose tile. 4608 el = 9216 B.
    __shared__ __align__(16) __hip_bfloat16 lbuf[4608];
    __hip_bfloat16* wp = lbuf + wave * 1152;

    bf16x8 aq0 = *(const bf16x8*)&qb[(size_t)(s0 + lc) * 64 + lg * 8];
    bf16x8 aq1 = *(const bf16x8*)&qb[(size_t)(s0 + lc) * 64 + 32 + lg * 8];

    f32x4 O[4] = {};
    f32x4 lsum = {};

    for (int t0 = 0; t0 < S; t0 += 64) {
        // V fragments first: latency overlaps QK+exp+writes below
        bf16x8 vf0[4], vf1[4];
        #pragma unroll
        for (int dt = 0; dt < 4; ++dt) {
            const __hip_bfloat16* vr = &vb[(size_t)(dt * 16 + lc) * S + t0 + lg * 8];
            vf0[dt] = *(const bf16x8*)vr;
            vf1[dt] = *(const bf16x8*)(vr + 32);
        }
        // QK^T for 64 keys (4 x 16), exp2 (q pre-scaled by log2e/64)
        f32x4 ex[4];
        #pragma unroll
        for (int nt = 0; nt < 4; ++nt) {
            const __hip_bfloat16* kr = &kb[(size_t)(t0 + nt * 16 + lc) * 64];
            bf16x8 b0 = *(const bf16x8*)&kr[lg * 8];
            bf16x8 b1 = *(const bf16x8*)&kr[32 + lg * 8];
            f32x4 s = {};
            s = mfma16(aq0, b0, s);
            s = mfma16(aq1, b1, s);
            #pragma unroll
            for (int r = 0; r < 4; ++r) ex[nt][r] = exp2f(s[r]);
        }
        lsum += ex[0] + ex[1] + ex[2] + ex[3];
        // P: C-layout -> LDS -> A-layout (per-wave round-trip; fenced)
        #pragma unroll
        for (int nt = 0; nt < 4; ++nt)
            #pragma unroll
            for (int r = 0; r < 4; ++r)
                wp[(lg * 4 + r) * 72 + nt * 16 + lc] = __float2bfloat16(ex[nt][r]);
        asm volatile("s_waitcnt lgkmcnt(0)" ::: "memory");
        bf16x8 pa0 = *(const bf16x8*)&wp[lc * 72 + lg * 8];
        bf16x8 pa1 = *(const bf16x8*)&wp[lc * 72 + 32 + lg * 8];
        asm volatile("" ::: "memory");
        #pragma unroll
        for (int dt = 0; dt < 4; ++dt) {
            O[dt] = mfma16(pa0, vf0[dt], O[dt]);
            O[dt] = mfma16(pa1, vf1[dt], O[dt]);
        }
    }
    // one-time cross-lane row-sum reduction (keys were spread over lc lanes)
    #pragma unroll
    for (int r = 0; r < 4; ++r) {
        float v = lsum[r];
        v += __shfl_xor(v, 1);
        v += __shfl_xor(v, 2);
        v += __shfl_xor(v, 4);
        v += __shfl_xor(v, 8);
        lsum[r] = 1.0f / v;
    }
    __syncthreads();   // all waves done with their P slices
    // O (C-layout: lane lc = d-col, row = q) -> lbuf[d][s], then coalesced store
    #pragma unroll
    for (int dt = 0; dt < 4; ++dt)
        #pragma unroll
        for (int r = 0; r < 4; ++r)
            lbuf[(dt * 16 + lc) * 72 + wave * 16 + lg * 4 + r] =
                __float2bfloat16(O[dt][r] * lsum[r]);
    __syncthreads();
    int row = tid >> 2, c8 = (tid & 3) * 8;
    size_t off = ((size_t)b * 512 + h * 64 + row) * S + blockIdx.x * 64;
    *(bf16x8*)&cT[off + c8]      = *(const bf16x8*)&lbuf[row * 72 + c8];
    *(bf16x8*)&cT[off + 32 + c8] = *(const bf16x8*)&lbuf[row * 72 + 32 + c8];
}

extern "C" void kernel_launch(void* const* d_in, const int* in_sizes, int n_in,
                              void* d_out, int out_size, void* d_ws, size_t ws_size,
                              hipStream_t stream) {
    using bf = __hip_bfloat16;
    bf* ws = (bf*)d_ws;
    int* flag = (int*)d_ws;
    bf* bqc = ws + 64;
    bf* bkc = ws + 576;
    bf* bvc = ws + 1088;
    bf* btc = ws + 1600;
    bf* boc = ws + 2320;
    bf* WqT = ws + 4096;       // [8][64][512]
    bf* WkT = ws + 266240;
    bf* WvT = ws + 528384;
    bf* Wtc = ws + 790528;     // [720][2048]
    bf* Woc = ws + 2265088;    // [512][512]
    bf* Xc  = ws + 2527232;    // [4][2048][512], dead after QKV gemms
    bf* cT  = ws + 2527232;    // [4][512][2048], overlays Xc
    bf* q   = ws + 6721536;    // [32][2048][64], dead after flash
    bf* up  = ws + 6721536;    // [4][720][512], overlays q
    bf* kk  = ws + 10915840;   // [32][2048][64]
    bf* vT  = ws + 15110144;   // [32][64][2048]

    probe_dtype<<<dim3(1), 256, 0, stream>>>((const unsigned*)d_in[0], flag);

    CTab tab;
    tab.t[0]  = { d_in[0],  Xc,  4194304, 0 };
    tab.t[1]  = { d_in[1],  WqT, 262144,  1 };
    tab.t[2]  = { d_in[2],  bqc, 512,     0 };
    tab.t[3]  = { d_in[3],  WkT, 262144,  1 };
    tab.t[4]  = { d_in[4],  bkc, 512,     0 };
    tab.t[5]  = { d_in[5],  WvT, 262144,  1 };
    tab.t[6]  = { d_in[6],  bvc, 512,     0 };
    tab.t[7]  = { d_in[7],  Wtc, 1474560, 0 };
    tab.t[8]  = { d_in[8],  btc, 720,     0 };
    tab.t[9]  = { d_in[9],  Woc, 262144,  0 };
    tab.t[10] = { d_in[10], boc, 512,     0 };
    convert_all<<<dim3(2048, 11), 256, 0, stream>>>(tab, flag);

    // q[h] = Xc*WqT^T + bq, PRE-SCALED by log2(e)/64 for fixed-max softmax
    const float qscale = 0.022542110013890054f;  // log2(e)/64
    gemm_bt<128, 64><<<dim3(1, 64, 8), 256, 0, stream>>>(
        Xc, WqT, q, 8192, 64, 512, 512, 512, 64,
        0, 0, 32768, 0, 524288, 0, nullptr, 0, bqc, 64, 1, nullptr, qscale);
    gemm_bt<128, 64><<<dim3(1, 64, 8), 256, 0, stream>>>(
        Xc, WkT, kk, 8192, 64, 512, 512, 512, 64,
        0, 0, 32768, 0, 524288, 0, nullptr, 0, bkc, 64, 1, nullptr, 1.0f);

    // vT[h,b] = WvT[h] * Xc[b]^T + bv (per-row)  (z1=h, z0=b)
    gemm_bt<64, 128><<<dim3(16, 1, 32), 256, 0, stream>>>(
        WvT, Xc, vT, 64, 2048, 512, 512, 512, 2048,
        32768, 0, 0, 1048576, 524288, 131072, bvc, 64, nullptr, 0, 4, nullptr, 1.0f);

    flash_attn<<<dim3(32, 32), 256, 0, stream>>>(q, kk, vT, cT);

    // up[b] = Wt * cT[b]^T + bt (per-row)   (z1 = b)
    gemm_bt<128, 128><<<dim3(4, 6, 4), 256, 0, stream>>>(
        Wtc, cT, up, 720, 512, 2048, 2048, 2048, 512,
        0, 0, 1048576, 0, 368640, 0, btc, 0, nullptr, 0, 1, nullptr, 1.0f);

    // out = up * Woc^T + bo (per-col); dtype per probe flag
    gemm_bt<128, 128><<<dim3(4, 23, 1), 256, 0, stream>>>(
        up, Woc, d_out, 2880, 512, 512, 512, 512, 512,
        0, 0, 0, 0, 0, 0, nullptr, 0, boc, 0, 1, flag, 1.0f);
}

// Round 6
// 313.303 us; speedup vs baseline: 1.4207x; 1.4084x over previous
//
#include <hip/hip_runtime.h>
#include <hip/hip_bf16.h>

// Model_3315714753203: B=4,S=2048,I=512,D=512,H=8,HD=64,P=720.
// fp32 inputs (probed) -> internal bf16. probe -> convert(+W transpose) ->
// GEMM q,k,vT -> flash attention (LDS-staged K/V, double-buffered prefetch,
// fixed-max softmax, deferred row-sum) -> GEMM up -> GEMM out.

typedef short bf16x8 __attribute__((ext_vector_type(8)));
typedef float f32x4 __attribute__((ext_vector_type(4)));
typedef const __attribute__((address_space(1))) void* gptr_t;
typedef __attribute__((address_space(3))) void* sptr_t;

__device__ __forceinline__ f32x4 mfma16(bf16x8 a, bf16x8 b, f32x4 c) {
    return __builtin_amdgcn_mfma_f32_16x16x32_bf16(a, b, c, 0, 0, 0);
}
__device__ __forceinline__ void async16(const void* g, void* l) {
    __builtin_amdgcn_global_load_lds((gptr_t)g, (sptr_t)l, 16, 0, 0);
}

// ---------------- dtype probe (decides fp32 vs bf16 decode at runtime)
__global__ void probe_dtype(const unsigned* __restrict__ x, int* __restrict__ flag) {
    __shared__ int cnt[256];
    int c = 0;
    for (int i = threadIdx.x; i < 1024; i += 256) {
        unsigned e = (x[i] >> 23) & 0xffu;
        c += (e >= 100u && e <= 145u) ? 1 : 0;
    }
    cnt[threadIdx.x] = c;
    __syncthreads();
    for (int s = 128; s > 0; s >>= 1) {
        if (threadIdx.x < s) cnt[threadIdx.x] += cnt[threadIdx.x + s];
        __syncthreads();
    }
    if (threadIdx.x == 0) *flag = (cnt[0] >= 512) ? 1 : 0;
}

// ---------------- convert all inputs to internal bf16 (mode1 = HID->HDI transpose)
struct CDesc { const void* s; __hip_bfloat16* d; int n; int mode; };
struct CTab  { CDesc t[11]; };

__global__ void convert_all(CTab tab, const int* __restrict__ flag) {
    CDesc de = tab.t[blockIdx.y];
    const int isF32 = *flag;
    for (int i = blockIdx.x * 256 + threadIdx.x; i < de.n; i += gridDim.x * 256) {
        int si = i;
        if (de.mode) {  // dst [h][d][i512]: i=(h*64+d)*512+ii  src [h][i512][d]
            int ii = i & 511, d = (i >> 9) & 63, h = i >> 15;
            si = (h * 512 + ii) * 64 + d;
        }
        float v = isF32 ? ((const float*)de.s)[si]
                        : (float)((const __hip_bfloat16*)de.s)[si];
        de.d[i] = __float2bfloat16(v);
    }
}

// ---------------- generic MFMA GEMM: C[M,N] = (A[M,K] * B[N,K]^T + bias) * cscale
template<int BM, int BN>
__global__ __launch_bounds__(256, 2) void gemm_bt(
    const __hip_bfloat16* __restrict__ A,
    const __hip_bfloat16* __restrict__ B,
    void* __restrict__ C,
    int M, int N, int K, int lda, int ldb, int ldc,
    long sA1, long sA0, long sB1, long sB0, long sC1, long sC0,
    const __hip_bfloat16* __restrict__ biasM, long sbM1,
    const __hip_bfloat16* __restrict__ biasN, long sbN1,
    int Z0, const int* __restrict__ outF32flag, float cscale)
{
    constexpr int BK = 64;
    const int z = blockIdx.z;
    const int z1 = z / Z0, z0 = z - z1 * Z0;
    A += (size_t)z1 * sA1 + (size_t)z0 * sA0;
    B += (size_t)z1 * sB1 + (size_t)z0 * sB0;
    const size_t cbase = (size_t)z1 * sC1 + (size_t)z0 * sC0;
    if (biasM) biasM += (size_t)z1 * sbM1;
    if (biasN) biasN += (size_t)z1 * sbN1;
    const int outF32 = outF32flag ? *outF32flag : 0;

    __shared__ __align__(16) __hip_bfloat16 lA[BM * BK];
    __shared__ __align__(16) __hip_bfloat16 lB[BN * BK];

    const int tid  = threadIdx.x;
    const int lane = tid & 63;
    const int wave = tid >> 6;
    const int m0 = blockIdx.y * BM;
    const int n0 = blockIdx.x * BN;
    constexpr int WM = BM / 2, WN = BN / 2, FM = WM / 16, FN = WN / 16;
    const int wm = (wave >> 1) * WM, wn = (wave & 1) * WN;
    const int lc = lane & 15, lg = lane >> 4;

    f32x4 acc[FM][FN] = {};

    constexpr int CA = BM * 8 / 256;
    constexpr int CB = BN * 8 / 256;

    for (int k0 = 0; k0 < K; k0 += BK) {
        #pragma unroll
        for (int j = 0; j < CA; ++j) {
            int ch = j * 256 + tid;
            int m = ch >> 3, kc = ch & 7;
            int mg = m0 + m; if (mg > M - 1) mg = M - 1;
            async16(&A[(size_t)mg * lda + k0 + kc * 8], &lA[ch * 8]);
        }
        #pragma unroll
        for (int j = 0; j < CB; ++j) {
            int ch = j * 256 + tid;
            int n = ch >> 3, kc = ch & 7;
            int ng = n0 + n; if (ng > N - 1) ng = N - 1;
            async16(&B[(size_t)ng * ldb + k0 + kc * 8], &lB[ch * 8]);
        }
        __syncthreads();
        #pragma unroll
        for (int ks = 0; ks < BK; ks += 32) {
            bf16x8 af[FM], bfr[FN];
            #pragma unroll
            for (int i = 0; i < FM; ++i)
                af[i] = *(const bf16x8*)&lA[(wm + i * 16 + lc) * BK + ks + lg * 8];
            #pragma unroll
            for (int j = 0; j < FN; ++j)
                bfr[j] = *(const bf16x8*)&lB[(wn + j * 16 + lc) * BK + ks + lg * 8];
            #pragma unroll
            for (int i = 0; i < FM; ++i)
                #pragma unroll
                for (int j = 0; j < FN; ++j)
                    acc[i][j] = mfma16(af[i], bfr[j], acc[i][j]);
        }
        __syncthreads();
    }

    #pragma unroll
    for (int i = 0; i < FM; ++i) {
        int rbase = m0 + wm + i * 16 + lg * 4;
        #pragma unroll
        for (int j = 0; j < FN; ++j) {
            int col = n0 + wn + j * 16 + lc;
            if (col >= N) continue;
            float bn = biasN ? (float)biasN[col] : 0.0f;
            #pragma unroll
            for (int r = 0; r < 4; ++r) {
                int row = rbase + r;
                if (row < M) {
                    float v = acc[i][j][r] + bn;
                    if (biasM) v += (float)biasM[row];
                    v *= cscale;
                    size_t idx = cbase + (size_t)row * ldc + col;
                    if (outF32) ((float*)C)[idx] = v;
                    else ((__hip_bfloat16*)C)[idx] = __float2bfloat16(v);
                }
            }
        }
    }
}

// ---------------- flash attention v3: LDS-staged K/V, double-buffered prefetch
// q pre-scaled by log2(e)/64 -> numerator 2^(q.k); fixed max; row-sum deferred.
// K/V tiles (64 keys) staged via global_load_lds into LDS shared by all 4
// waves; tile t+1 issued at top of iter t, drained at the single barrier ->
// VMEM latency overlaps compute (r5 had 16 private VMEM loads/wave/iter, all
// latency-exposed; now 4 shared staging insts/thread/iter).
// q,k: [H*B][S][64]; vT: [H*B][64][S]; out cT: [B][512][S] (combined^T)
__global__ __launch_bounds__(256, 2) void flash_attn(
    const __hip_bfloat16* __restrict__ q,
    const __hip_bfloat16* __restrict__ k,
    const __hip_bfloat16* __restrict__ vT,
    __hip_bfloat16* __restrict__ cT)
{
    const int S = 2048;
    const int h = blockIdx.y >> 2, b = blockIdx.y & 3;
    const int tid = threadIdx.x, lane = tid & 63, wave = tid >> 6;
    const int lc = lane & 15, lg = lane >> 4;
    const int s0 = blockIdx.x * 64 + wave * 16;

    const __hip_bfloat16* qb = q  + (size_t)(h * 4 + b) * S * 64;
    const __hip_bfloat16* kb = k  + (size_t)(h * 4 + b) * S * 64;
    const __hip_bfloat16* vb = vT + (size_t)(h * 4 + b) * 64 * S;

    // K/V double buffers: [key|d][64] row-major 8KB each; P/epilogue 9.2KB.
    __shared__ __align__(16) __hip_bfloat16 lk[2][4096];
    __shared__ __align__(16) __hip_bfloat16 lv[2][4096];
    __shared__ __align__(16) __hip_bfloat16 lbuf[4608];   // P stride 72 / epilogue
    __hip_bfloat16* wp = lbuf + wave * 1152;

    bf16x8 aq0 = *(const bf16x8*)&qb[(size_t)(s0 + lc) * 64 + lg * 8];
    bf16x8 aq1 = *(const bf16x8*)&qb[(size_t)(s0 + lc) * 64 + 32 + lg * 8];

    // stage tile 0 into buffer 0: k rows 0..63, v cols 0..63 (both 64x64)
    #pragma unroll
    for (int j = 0; j < 2; ++j) {
        int ch = j * 256 + tid;
        int row = ch >> 3, c8 = (ch & 7) * 8;
        async16(&kb[(size_t)row * 64 + c8], &lk[0][ch * 8]);
        async16(&vb[(size_t)row * S  + c8], &lv[0][ch * 8]);
    }
    __syncthreads();

    f32x4 O[4] = {};
    f32x4 lsum = {};

    for (int t = 0; t < 32; ++t) {
        const int cur = t & 1, nxt = cur ^ 1;
        // prefetch tile t+1 (fire-and-forget; drained at end-of-iter barrier)
        if (t + 1 < 32) {
            const int t1 = (t + 1) * 64;
            #pragma unroll
            for (int j = 0; j < 2; ++j) {
                int ch = j * 256 + tid;
                int row = ch >> 3, c8 = (ch & 7) * 8;
                async16(&kb[(size_t)(t1 + row) * 64 + c8], &lk[nxt][ch * 8]);
                async16(&vb[(size_t)row * S + t1 + c8],    &lv[nxt][ch * 8]);
            }
        }
        // QK^T for 64 keys (4 x 16) from LDS, exp2 (q pre-scaled)
        f32x4 ex[4];
        #pragma unroll
        for (int nt = 0; nt < 4; ++nt) {
            bf16x8 b0 = *(const bf16x8*)&lk[cur][(nt * 16 + lc) * 64 + lg * 8];
            bf16x8 b1 = *(const bf16x8*)&lk[cur][(nt * 16 + lc) * 64 + 32 + lg * 8];
            f32x4 s = {};
            s = mfma16(aq0, b0, s);
            s = mfma16(aq1, b1, s);
            #pragma unroll
            for (int r = 0; r < 4; ++r) ex[nt][r] = exp2f(s[r]);
        }
        lsum += ex[0] + ex[1] + ex[2] + ex[3];
        // P: C-layout -> LDS -> A-layout (per-wave round-trip; fenced)
        #pragma unroll
        for (int nt = 0; nt < 4; ++nt)
            #pragma unroll
            for (int r = 0; r < 4; ++r)
                wp[(lg * 4 + r) * 72 + nt * 16 + lc] = __float2bfloat16(ex[nt][r]);
        asm volatile("s_waitcnt lgkmcnt(0)" ::: "memory");
        bf16x8 pa0 = *(const bf16x8*)&wp[lc * 72 + lg * 8];
        bf16x8 pa1 = *(const bf16x8*)&wp[lc * 72 + 32 + lg * 8];
        asm volatile("" ::: "memory");
        // PV from LDS V tile
        #pragma unroll
        for (int dt = 0; dt < 4; ++dt) {
            bf16x8 vf0 = *(const bf16x8*)&lv[cur][(dt * 16 + lc) * 64 + lg * 8];
            bf16x8 vf1 = *(const bf16x8*)&lv[cur][(dt * 16 + lc) * 64 + 32 + lg * 8];
            O[dt] = mfma16(pa0, vf0, O[dt]);
            O[dt] = mfma16(pa1, vf1, O[dt]);
        }
        __syncthreads();   // drains prefetch (overlapped w/ compute) + guards buf reuse
    }
    // one-time cross-lane row-sum reduction (keys were spread over lc lanes)
    #pragma unroll
    for (int r = 0; r < 4; ++r) {
        float v = lsum[r];
        v += __shfl_xor(v, 1);
        v += __shfl_xor(v, 2);
        v += __shfl_xor(v, 4);
        v += __shfl_xor(v, 8);
        lsum[r] = 1.0f / v;
    }
    // O (C-layout: lane lc = d-col, row = q) -> lbuf[d][s], then coalesced store
    #pragma unroll
    for (int dt = 0; dt < 4; ++dt)
        #pragma unroll
        for (int r = 0; r < 4; ++r)
            lbuf[(dt * 16 + lc) * 72 + wave * 16 + lg * 4 + r] =
                __float2bfloat16(O[dt][r] * lsum[r]);
    __syncthreads();
    int row = tid >> 2, c8 = (tid & 3) * 8;
    size_t off = ((size_t)b * 512 + h * 64 + row) * S + blockIdx.x * 64;
    *(bf16x8*)&cT[off + c8]      = *(const bf16x8*)&lbuf[row * 72 + c8];
    *(bf16x8*)&cT[off + 32 + c8] = *(const bf16x8*)&lbuf[row * 72 + 32 + c8];
}

extern "C" void kernel_launch(void* const* d_in, const int* in_sizes, int n_in,
                              void* d_out, int out_size, void* d_ws, size_t ws_size,
                              hipStream_t stream) {
    using bf = __hip_bfloat16;
    bf* ws = (bf*)d_ws;
    int* flag = (int*)d_ws;
    bf* bqc = ws + 64;
    bf* bkc = ws + 576;
    bf* bvc = ws + 1088;
    bf* btc = ws + 1600;
    bf* boc = ws + 2320;
    bf* WqT = ws + 4096;       // [8][64][512]
    bf* WkT = ws + 266240;
    bf* WvT = ws + 528384;
    bf* Wtc = ws + 790528;     // [720][2048]
    bf* Woc = ws + 2265088;    // [512][512]
    bf* Xc  = ws + 2527232;    // [4][2048][512], dead after QKV gemms
    bf* cT  = ws + 2527232;    // [4][512][2048], overlays Xc
    bf* q   = ws + 6721536;    // [32][2048][64], dead after flash
    bf* up  = ws + 6721536;    // [4][720][512], overlays q
    bf* kk  = ws + 10915840;   // [32][2048][64]
    bf* vT  = ws + 15110144;   // [32][64][2048]

    probe_dtype<<<dim3(1), 256, 0, stream>>>((const unsigned*)d_in[0], flag);

    CTab tab;
    tab.t[0]  = { d_in[0],  Xc,  4194304, 0 };
    tab.t[1]  = { d_in[1],  WqT, 262144,  1 };
    tab.t[2]  = { d_in[2],  bqc, 512,     0 };
    tab.t[3]  = { d_in[3],  WkT, 262144,  1 };
    tab.t[4]  = { d_in[4],  bkc, 512,     0 };
    tab.t[5]  = { d_in[5],  WvT, 262144,  1 };
    tab.t[6]  = { d_in[6],  bvc, 512,     0 };
    tab.t[7]  = { d_in[7],  Wtc, 1474560, 0 };
    tab.t[8]  = { d_in[8],  btc, 720,     0 };
    tab.t[9]  = { d_in[9],  Woc, 262144,  0 };
    tab.t[10] = { d_in[10], boc, 512,     0 };
    convert_all<<<dim3(2048, 11), 256, 0, stream>>>(tab, flag);

    // q[h] = Xc*WqT^T + bq, PRE-SCALED by log2(e)/64 for fixed-max softmax
    const float qscale = 0.022542110013890054f;  // log2(e)/64
    gemm_bt<128, 64><<<dim3(1, 64, 8), 256, 0, stream>>>(
        Xc, WqT, q, 8192, 64, 512, 512, 512, 64,
        0, 0, 32768, 0, 524288, 0, nullptr, 0, bqc, 64, 1, nullptr, qscale);
    gemm_bt<128, 64><<<dim3(1, 64, 8), 256, 0, stream>>>(
        Xc, WkT, kk, 8192, 64, 512, 512, 512, 64,
        0, 0, 32768, 0, 524288, 0, nullptr, 0, bkc, 64, 1, nullptr, 1.0f);

    // vT[h,b] = WvT[h] * Xc[b]^T + bv (per-row)  (z1=h, z0=b)
    gemm_bt<64, 128><<<dim3(16, 1, 32), 256, 0, stream>>>(
        WvT, Xc, vT, 64, 2048, 512, 512, 512, 2048,
        32768, 0, 0, 1048576, 524288, 131072, bvc, 64, nullptr, 0, 4, nullptr, 1.0f);

    flash_attn<<<dim3(32, 32), 256, 0, stream>>>(q, kk, vT, cT);

    // up[b] = Wt * cT[b]^T + bt (per-row)   (z1 = b)
    gemm_bt<128, 128><<<dim3(4, 6, 4), 256, 0, stream>>>(
        Wtc, cT, up, 720, 512, 2048, 2048, 2048, 512,
        0, 0, 1048576, 0, 368640, 0, btc, 0, nullptr, 0, 1, nullptr, 1.0f);

    // out = up * Woc^T + bo (per-col); dtype per probe flag
    gemm_bt<128, 128><<<dim3(4, 23, 1), 256, 0, stream>>>(
        up, Woc, d_out, 2880, 512, 512, 512, 512, 512,
        0, 0, 0, 0, 0, 0, nullptr, 0, boc, 0, 1, flag, 1.0f);
}

// Round 7
// 271.381 us; speedup vs baseline: 1.6402x; 1.1545x over previous
//
#include <hip/hip_runtime.h>
#include <hip/hip_bf16.h>

// Model_3315714753203: B=4,S=2048,I=512,D=512,H=8,HD=64,P=720.
// fp32 inputs (probed) -> internal bf16. probe -> convert(+W transpose) ->
// GEMM q,k,vT -> flash attention (LDS-staged K/V w/ XOR-swizzled chunk layout,
// double-buffered prefetch, 32 q-rows/wave, fixed-max softmax, deferred
// row-sum) -> GEMM up -> GEMM out.

typedef short bf16x8 __attribute__((ext_vector_type(8)));
typedef float f32x4 __attribute__((ext_vector_type(4)));
typedef const __attribute__((address_space(1))) void* gptr_t;
typedef __attribute__((address_space(3))) void* sptr_t;

__device__ __forceinline__ f32x4 mfma16(bf16x8 a, bf16x8 b, f32x4 c) {
    return __builtin_amdgcn_mfma_f32_16x16x32_bf16(a, b, c, 0, 0, 0);
}
__device__ __forceinline__ void async16(const void* g, void* l) {
    __builtin_amdgcn_global_load_lds((gptr_t)g, (sptr_t)l, 16, 0, 0);
}

// ---------------- dtype probe (decides fp32 vs bf16 decode at runtime)
__global__ void probe_dtype(const unsigned* __restrict__ x, int* __restrict__ flag) {
    __shared__ int cnt[256];
    int c = 0;
    for (int i = threadIdx.x; i < 1024; i += 256) {
        unsigned e = (x[i] >> 23) & 0xffu;
        c += (e >= 100u && e <= 145u) ? 1 : 0;
    }
    cnt[threadIdx.x] = c;
    __syncthreads();
    for (int s = 128; s > 0; s >>= 1) {
        if (threadIdx.x < s) cnt[threadIdx.x] += cnt[threadIdx.x + s];
        __syncthreads();
    }
    if (threadIdx.x == 0) *flag = (cnt[0] >= 512) ? 1 : 0;
}

// ---------------- convert all inputs to internal bf16 (mode1 = HID->HDI transpose)
struct CDesc { const void* s; __hip_bfloat16* d; int n; int mode; };
struct CTab  { CDesc t[11]; };

__global__ void convert_all(CTab tab, const int* __restrict__ flag) {
    CDesc de = tab.t[blockIdx.y];
    const int isF32 = *flag;
    for (int i = blockIdx.x * 256 + threadIdx.x; i < de.n; i += gridDim.x * 256) {
        int si = i;
        if (de.mode) {  // dst [h][d][i512]: i=(h*64+d)*512+ii  src [h][i512][d]
            int ii = i & 511, d = (i >> 9) & 63, h = i >> 15;
            si = (h * 512 + ii) * 64 + d;
        }
        float v = isF32 ? ((const float*)de.s)[si]
                        : (float)((const __hip_bfloat16*)de.s)[si];
        de.d[i] = __float2bfloat16(v);
    }
}

// ---------------- generic MFMA GEMM: C[M,N] = (A[M,K] * B[N,K]^T + bias) * cscale
template<int BM, int BN>
__global__ __launch_bounds__(256, 2) void gemm_bt(
    const __hip_bfloat16* __restrict__ A,
    const __hip_bfloat16* __restrict__ B,
    void* __restrict__ C,
    int M, int N, int K, int lda, int ldb, int ldc,
    long sA1, long sA0, long sB1, long sB0, long sC1, long sC0,
    const __hip_bfloat16* __restrict__ biasM, long sbM1,
    const __hip_bfloat16* __restrict__ biasN, long sbN1,
    int Z0, const int* __restrict__ outF32flag, float cscale)
{
    constexpr int BK = 64;
    const int z = blockIdx.z;
    const int z1 = z / Z0, z0 = z - z1 * Z0;
    A += (size_t)z1 * sA1 + (size_t)z0 * sA0;
    B += (size_t)z1 * sB1 + (size_t)z0 * sB0;
    const size_t cbase = (size_t)z1 * sC1 + (size_t)z0 * sC0;
    if (biasM) biasM += (size_t)z1 * sbM1;
    if (biasN) biasN += (size_t)z1 * sbN1;
    const int outF32 = outF32flag ? *outF32flag : 0;

    __shared__ __align__(16) __hip_bfloat16 lA[BM * BK];
    __shared__ __align__(16) __hip_bfloat16 lB[BN * BK];

    const int tid  = threadIdx.x;
    const int lane = tid & 63;
    const int wave = tid >> 6;
    const int m0 = blockIdx.y * BM;
    const int n0 = blockIdx.x * BN;
    constexpr int WM = BM / 2, WN = BN / 2, FM = WM / 16, FN = WN / 16;
    const int wm = (wave >> 1) * WM, wn = (wave & 1) * WN;
    const int lc = lane & 15, lg = lane >> 4;

    f32x4 acc[FM][FN] = {};

    constexpr int CA = BM * 8 / 256;
    constexpr int CB = BN * 8 / 256;

    for (int k0 = 0; k0 < K; k0 += BK) {
        #pragma unroll
        for (int j = 0; j < CA; ++j) {
            int ch = j * 256 + tid;
            int m = ch >> 3, kc = ch & 7;
            int mg = m0 + m; if (mg > M - 1) mg = M - 1;
            async16(&A[(size_t)mg * lda + k0 + kc * 8], &lA[ch * 8]);
        }
        #pragma unroll
        for (int j = 0; j < CB; ++j) {
            int ch = j * 256 + tid;
            int n = ch >> 3, kc = ch & 7;
            int ng = n0 + n; if (ng > N - 1) ng = N - 1;
            async16(&B[(size_t)ng * ldb + k0 + kc * 8], &lB[ch * 8]);
        }
        __syncthreads();
        #pragma unroll
        for (int ks = 0; ks < BK; ks += 32) {
            bf16x8 af[FM], bfr[FN];
            #pragma unroll
            for (int i = 0; i < FM; ++i)
                af[i] = *(const bf16x8*)&lA[(wm + i * 16 + lc) * BK + ks + lg * 8];
            #pragma unroll
            for (int j = 0; j < FN; ++j)
                bfr[j] = *(const bf16x8*)&lB[(wn + j * 16 + lc) * BK + ks + lg * 8];
            #pragma unroll
            for (int i = 0; i < FM; ++i)
                #pragma unroll
                for (int j = 0; j < FN; ++j)
                    acc[i][j] = mfma16(af[i], bfr[j], acc[i][j]);
        }
        __syncthreads();
    }

    #pragma unroll
    for (int i = 0; i < FM; ++i) {
        int rbase = m0 + wm + i * 16 + lg * 4;
        #pragma unroll
        for (int j = 0; j < FN; ++j) {
            int col = n0 + wn + j * 16 + lc;
            if (col >= N) continue;
            float bn = biasN ? (float)biasN[col] : 0.0f;
            #pragma unroll
            for (int r = 0; r < 4; ++r) {
                int row = rbase + r;
                if (row < M) {
                    float v = acc[i][j][r] + bn;
                    if (biasM) v += (float)biasM[row];
                    v *= cscale;
                    size_t idx = cbase + (size_t)row * ldc + col;
                    if (outF32) ((float*)C)[idx] = v;
                    else ((__hip_bfloat16*)C)[idx] = __float2bfloat16(v);
                }
            }
        }
    }
}

// ---------------- flash attention v4
// 32 q-rows/wave (128/block). K/V staged via global_load_lds with XOR chunk
// swizzle (c_lds = c_g ^ (row&7)): fragment reads hit all 8 LDS bank-groups
// (r6 layout hit only 4 -> 16-way conflicts, 26M stall cycles). V fragments
// reused across both q-subtiles. q pre-scaled by log2(e)/64; fixed-max
// softmax (scores bounded); row-sum deferred to epilogue.
// q,k: [H*B][S][64]; vT: [H*B][64][S]; out cT: [B][512][S] (combined^T)
__global__ __launch_bounds__(256, 2) void flash_attn(
    const __hip_bfloat16* __restrict__ q,
    const __hip_bfloat16* __restrict__ k,
    const __hip_bfloat16* __restrict__ vT,
    __hip_bfloat16* __restrict__ cT)
{
    const int S = 2048;
    const int h = blockIdx.y >> 2, b = blockIdx.y & 3;
    const int tid = threadIdx.x, lane = tid & 63, wave = tid >> 6;
    const int lc = lane & 15, lg = lane >> 4;
    const int s0 = blockIdx.x * 128 + wave * 32;

    const __hip_bfloat16* qb = q  + (size_t)(h * 4 + b) * S * 64;
    const __hip_bfloat16* kb = k  + (size_t)(h * 4 + b) * S * 64;
    const __hip_bfloat16* vb = vT + (size_t)(h * 4 + b) * 64 * S;

    __shared__ __align__(16) __hip_bfloat16 lk[2][4096];
    __shared__ __align__(16) __hip_bfloat16 lv[2][4096];
    __shared__ __align__(16) __hip_bfloat16 lbuf[9216];  // P (4w x 32 x 72) / epilogue (64 x 136)
    __hip_bfloat16* wp = lbuf + wave * 2304;

    // q fragments: 2 subtiles x 2 K-halves
    bf16x8 aq[2][2];
    #pragma unroll
    for (int f = 0; f < 2; ++f)
        #pragma unroll
        for (int hh = 0; hh < 2; ++hh)
            aq[f][hh] = *(const bf16x8*)&qb[(size_t)(s0 + f * 16 + lc) * 64 + hh * 32 + lg * 8];

    // stage tile 0 (swizzled)
    #pragma unroll
    for (int j = 0; j < 2; ++j) {
        int ch = j * 256 + tid;
        int row = ch >> 3, cg = (ch & 7) ^ (row & 7);
        async16(&kb[(size_t)row * 64 + cg * 8], &lk[0][ch * 8]);
        async16(&vb[(size_t)row * S  + cg * 8], &lv[0][ch * 8]);
    }
    __syncthreads();

    f32x4 O[2][4] = {};
    f32x4 lsum[2] = {};

    for (int t = 0; t < 32; ++t) {
        const int cur = t & 1, nxt = cur ^ 1;
        if (t + 1 < 32) {   // prefetch tile t+1 (drained at end-of-iter barrier)
            const int t1 = (t + 1) * 64;
            #pragma unroll
            for (int j = 0; j < 2; ++j) {
                int ch = j * 256 + tid;
                int row = ch >> 3, cg = (ch & 7) ^ (row & 7);
                async16(&kb[(size_t)(t1 + row) * 64 + cg * 8], &lk[nxt][ch * 8]);
                async16(&vb[(size_t)row * S + t1 + cg * 8],    &lv[nxt][ch * 8]);
            }
        }
        // QK^T for 64 keys x 32 q rows, exp2 (q pre-scaled)
        f32x4 ex[2][4];
        #pragma unroll
        for (int nt = 0; nt < 4; ++nt) {
            int krow = nt * 16 + lc, sw = krow & 7;
            bf16x8 b0 = *(const bf16x8*)&lk[cur][krow * 64 + ((0 + lg) ^ sw) * 8];
            bf16x8 b1 = *(const bf16x8*)&lk[cur][krow * 64 + ((4 + lg) ^ sw) * 8];
            #pragma unroll
            for (int f = 0; f < 2; ++f) {
                f32x4 s = {};
                s = mfma16(aq[f][0], b0, s);
                s = mfma16(aq[f][1], b1, s);
                #pragma unroll
                for (int r = 0; r < 4; ++r) ex[f][nt][r] = exp2f(s[r]);
            }
        }
        #pragma unroll
        for (int f = 0; f < 2; ++f)
            lsum[f] += ex[f][0] + ex[f][1] + ex[f][2] + ex[f][3];
        // P: C-layout -> LDS -> A-layout (per-wave round-trip; fenced)
        #pragma unroll
        for (int f = 0; f < 2; ++f)
            #pragma unroll
            for (int nt = 0; nt < 4; ++nt)
                #pragma unroll
                for (int r = 0; r < 4; ++r)
                    wp[(f * 16 + lg * 4 + r) * 72 + nt * 16 + lc] =
                        __float2bfloat16(ex[f][nt][r]);
        asm volatile("s_waitcnt lgkmcnt(0)" ::: "memory");
        bf16x8 pa[2][2];
        #pragma unroll
        for (int f = 0; f < 2; ++f) {
            pa[f][0] = *(const bf16x8*)&wp[(f * 16 + lc) * 72 + lg * 8];
            pa[f][1] = *(const bf16x8*)&wp[(f * 16 + lc) * 72 + 32 + lg * 8];
        }
        asm volatile("" ::: "memory");
        // PV: V fragments shared across both q subtiles
        #pragma unroll
        for (int dt = 0; dt < 4; ++dt) {
            int vrow = dt * 16 + lc, sw = vrow & 7;
            bf16x8 vf0 = *(const bf16x8*)&lv[cur][vrow * 64 + ((0 + lg) ^ sw) * 8];
            bf16x8 vf1 = *(const bf16x8*)&lv[cur][vrow * 64 + ((4 + lg) ^ sw) * 8];
            #pragma unroll
            for (int f = 0; f < 2; ++f) {
                O[f][dt] = mfma16(pa[f][0], vf0, O[f][dt]);
                O[f][dt] = mfma16(pa[f][1], vf1, O[f][dt]);
            }
        }
        __syncthreads();   // guards buffer swap + drains prefetch (overlapped)
    }
    // one-time cross-lane row-sum reduction (keys spread over lc lanes)
    float inv[2][4];
    #pragma unroll
    for (int f = 0; f < 2; ++f)
        #pragma unroll
        for (int r = 0; r < 4; ++r) {
            float v = lsum[f][r];
            v += __shfl_xor(v, 1);
            v += __shfl_xor(v, 2);
            v += __shfl_xor(v, 4);
            v += __shfl_xor(v, 8);
            inv[f][r] = 1.0f / v;
        }
    // O (C-layout: col=d on lc, row=q) -> lbuf[d][s] (stride 136), coalesced store
    #pragma unroll
    for (int f = 0; f < 2; ++f)
        #pragma unroll
        for (int dt = 0; dt < 4; ++dt)
            #pragma unroll
            for (int r = 0; r < 4; ++r)
                lbuf[(dt * 16 + lc) * 136 + wave * 32 + f * 16 + lg * 4 + r] =
                    __float2bfloat16(O[f][dt][r] * inv[f][r]);
    __syncthreads();
    int row = tid >> 2, c0 = (tid & 3) * 32;   // 64 rows x 128 cols
    size_t off = ((size_t)b * 512 + h * 64 + row) * S + blockIdx.x * 128 + c0;
    #pragma unroll
    for (int cc = 0; cc < 4; ++cc)
        *(bf16x8*)&cT[off + cc * 8] = *(const bf16x8*)&lbuf[row * 136 + c0 + cc * 8];
}

extern "C" void kernel_launch(void* const* d_in, const int* in_sizes, int n_in,
                              void* d_out, int out_size, void* d_ws, size_t ws_size,
                              hipStream_t stream) {
    using bf = __hip_bfloat16;
    bf* ws = (bf*)d_ws;
    int* flag = (int*)d_ws;
    bf* bqc = ws + 64;
    bf* bkc = ws + 576;
    bf* bvc = ws + 1088;
    bf* btc = ws + 1600;
    bf* boc = ws + 2320;
    bf* WqT = ws + 4096;       // [8][64][512]
    bf* WkT = ws + 266240;
    bf* WvT = ws + 528384;
    bf* Wtc = ws + 790528;     // [720][2048]
    bf* Woc = ws + 2265088;    // [512][512]
    bf* Xc  = ws + 2527232;    // [4][2048][512], dead after QKV gemms
    bf* cT  = ws + 2527232;    // [4][512][2048], overlays Xc
    bf* q   = ws + 6721536;    // [32][2048][64], dead after flash
    bf* up  = ws + 6721536;    // [4][720][512], overlays q
    bf* kk  = ws + 10915840;   // [32][2048][64]
    bf* vT  = ws + 15110144;   // [32][64][2048]

    probe_dtype<<<dim3(1), 256, 0, stream>>>((const unsigned*)d_in[0], flag);

    CTab tab;
    tab.t[0]  = { d_in[0],  Xc,  4194304, 0 };
    tab.t[1]  = { d_in[1],  WqT, 262144,  1 };
    tab.t[2]  = { d_in[2],  bqc, 512,     0 };
    tab.t[3]  = { d_in[3],  WkT, 262144,  1 };
    tab.t[4]  = { d_in[4],  bkc, 512,     0 };
    tab.t[5]  = { d_in[5],  WvT, 262144,  1 };
    tab.t[6]  = { d_in[6],  bvc, 512,     0 };
    tab.t[7]  = { d_in[7],  Wtc, 1474560, 0 };
    tab.t[8]  = { d_in[8],  btc, 720,     0 };
    tab.t[9]  = { d_in[9],  Woc, 262144,  0 };
    tab.t[10] = { d_in[10], boc, 512,     0 };
    convert_all<<<dim3(2048, 11), 256, 0, stream>>>(tab, flag);

    // q[h] = Xc*WqT^T + bq, PRE-SCALED by log2(e)/64 for fixed-max softmax
    const float qscale = 0.022542110013890054f;  // log2(e)/64
    gemm_bt<128, 64><<<dim3(1, 64, 8), 256, 0, stream>>>(
        Xc, WqT, q, 8192, 64, 512, 512, 512, 64,
        0, 0, 32768, 0, 524288, 0, nullptr, 0, bqc, 64, 1, nullptr, qscale);
    gemm_bt<128, 64><<<dim3(1, 64, 8), 256, 0, stream>>>(
        Xc, WkT, kk, 8192, 64, 512, 512, 512, 64,
        0, 0, 32768, 0, 524288, 0, nullptr, 0, bkc, 64, 1, nullptr, 1.0f);

    // vT[h,b] = WvT[h] * Xc[b]^T + bv (per-row)  (z1=h, z0=b)
    gemm_bt<64, 128><<<dim3(16, 1, 32), 256, 0, stream>>>(
        WvT, Xc, vT, 64, 2048, 512, 512, 512, 2048,
        32768, 0, 0, 1048576, 524288, 131072, bvc, 64, nullptr, 0, 4, nullptr, 1.0f);

    flash_attn<<<dim3(16, 32), 256, 0, stream>>>(q, kk, vT, cT);

    // up[b] = Wt * cT[b]^T + bt (per-row)   (z1 = b); BN=64 -> 192 blocks
    gemm_bt<128, 64><<<dim3(8, 6, 4), 256, 0, stream>>>(
        Wtc, cT, up, 720, 512, 2048, 2048, 2048, 512,
        0, 0, 1048576, 0, 368640, 0, btc, 0, nullptr, 0, 1, nullptr, 1.0f);

    // out = up * Woc^T + bo (per-col); dtype per probe flag; 184 blocks
    gemm_bt<128, 64><<<dim3(8, 23, 1), 256, 0, stream>>>(
        up, Woc, d_out, 2880, 512, 512, 512, 512, 512,
        0, 0, 0, 0, 0, 0, nullptr, 0, boc, 0, 1, flag, 1.0f);
}

// Round 9
// 252.624 us; speedup vs baseline: 1.7620x; 1.0742x over previous
//
#include <hip/hip_runtime.h>
#include <hip/hip_bf16.h>

// Model_3315714753203: B=4,S=2048,I=512,D=512,H=8,HD=64,P=720.
// fp32 inputs (probed) -> internal bf16. probe -> convert(+W transpose) ->
// GEMM qk(merged) , vT -> flash attention v5 (K=16 MFMA chaining: S^T C-regs
// feed PV as B-operand directly; no P LDS round-trip, no in-loop fence) ->
// GEMM up -> GEMM out.

typedef short bf16x8 __attribute__((ext_vector_type(8)));
typedef short short4v __attribute__((ext_vector_type(4)));
typedef float f32x4 __attribute__((ext_vector_type(4)));
typedef const __attribute__((address_space(1))) void* gptr_t;
typedef __attribute__((address_space(3))) void* sptr_t;

__device__ __forceinline__ f32x4 mfma16(bf16x8 a, bf16x8 b, f32x4 c) {
    return __builtin_amdgcn_mfma_f32_16x16x32_bf16(a, b, c, 0, 0, 0);
}
// K=16 bf16 MFMA. __has_builtin is target-dependent: 1 on the gfx950 device
// pass (mai-insts), 0 on the host pass -> host gets a never-executed stub
// (round-8 failure: the fallback branch used a nonexistent builtin name).
__device__ __forceinline__ f32x4 mfma16k(short4v a, short4v b, f32x4 c) {
#if __has_builtin(__builtin_amdgcn_mfma_f32_16x16x16bf16_1k)
    return __builtin_amdgcn_mfma_f32_16x16x16bf16_1k(a, b, c, 0, 0, 0);
#else
    (void)a; (void)b; return c;   // host-pass stub only
#endif
}
__device__ __forceinline__ void async16(const void* g, void* l) {
    __builtin_amdgcn_global_load_lds((gptr_t)g, (sptr_t)l, 16, 0, 0);
}
// pack 4 f32 -> 4 bf16 (round-half-up: +0x8000 then take high 16; ~1.5 inst/elem)
__device__ __forceinline__ short4v pack_bf16x4(f32x4 v) {
    unsigned a = __builtin_bit_cast(unsigned, v[0]) + 0x8000u;
    unsigned b = __builtin_bit_cast(unsigned, v[1]) + 0x8000u;
    unsigned c = __builtin_bit_cast(unsigned, v[2]) + 0x8000u;
    unsigned d = __builtin_bit_cast(unsigned, v[3]) + 0x8000u;
    int2 t;
    t.x = (int)__builtin_amdgcn_perm(b, a, 0x07060302u);  // [a.hi16, b.hi16]
    t.y = (int)__builtin_amdgcn_perm(d, c, 0x07060302u);  // [c.hi16, d.hi16]
    return __builtin_bit_cast(short4v, t);
}

// ---------------- dtype probe (decides fp32 vs bf16 decode at runtime)
__global__ void probe_dtype(const unsigned* __restrict__ x, int* __restrict__ flag) {
    __shared__ int cnt[256];
    int c = 0;
    for (int i = threadIdx.x; i < 1024; i += 256) {
        unsigned e = (x[i] >> 23) & 0xffu;
        c += (e >= 100u && e <= 145u) ? 1 : 0;
    }
    cnt[threadIdx.x] = c;
    __syncthreads();
    for (int s = 128; s > 0; s >>= 1) {
        if (threadIdx.x < s) cnt[threadIdx.x] += cnt[threadIdx.x + s];
        __syncthreads();
    }
    if (threadIdx.x == 0) *flag = (cnt[0] >= 512) ? 1 : 0;
}

// ---------------- convert all inputs to internal bf16 (mode1 = HID->HDI transpose)
struct CDesc { const void* s; __hip_bfloat16* d; int n; int mode; };
struct CTab  { CDesc t[11]; };

__global__ void convert_all(CTab tab, const int* __restrict__ flag) {
    CDesc de = tab.t[blockIdx.y];
    const int isF32 = *flag;
    for (int i = blockIdx.x * 256 + threadIdx.x; i < de.n; i += gridDim.x * 256) {
        int si = i;
        if (de.mode) {  // dst [h][d][i512]: i=(h*64+d)*512+ii  src [h][i512][d]
            int ii = i & 511, d = (i >> 9) & 63, h = i >> 15;
            si = (h * 512 + ii) * 64 + d;
        }
        float v = isF32 ? ((const float*)de.s)[si]
                        : (float)((const __hip_bfloat16*)de.s)[si];
        de.d[i] = __float2bfloat16(v);
    }
}

// ---------------- generic MFMA GEMM: C[M,N] = A[M,K]*B[N,K]^T + bias; *cscale if z1<scaleZmax
template<int BM, int BN>
__global__ __launch_bounds__(256, 2) void gemm_bt(
    const __hip_bfloat16* __restrict__ A,
    const __hip_bfloat16* __restrict__ B,
    void* __restrict__ C,
    int M, int N, int K, int lda, int ldb, int ldc,
    long sA1, long sA0, long sB1, long sB0, long sC1, long sC0,
    const __hip_bfloat16* __restrict__ biasM, long sbM1,
    const __hip_bfloat16* __restrict__ biasN, long sbN1,
    int Z0, const int* __restrict__ outF32flag, float cscale, int scaleZmax)
{
    constexpr int BK = 64;
    const int z = blockIdx.z;
    const int z1 = z / Z0, z0 = z - z1 * Z0;
    A += (size_t)z1 * sA1 + (size_t)z0 * sA0;
    B += (size_t)z1 * sB1 + (size_t)z0 * sB0;
    const size_t cbase = (size_t)z1 * sC1 + (size_t)z0 * sC0;
    if (biasM) biasM += (size_t)z1 * sbM1;
    if (biasN) biasN += (size_t)z1 * sbN1;
    const int outF32 = outF32flag ? *outF32flag : 0;
    const float csc = (z1 < scaleZmax) ? cscale : 1.0f;

    __shared__ __align__(16) __hip_bfloat16 lA[BM * BK];
    __shared__ __align__(16) __hip_bfloat16 lB[BN * BK];

    const int tid  = threadIdx.x;
    const int lane = tid & 63;
    const int wave = tid >> 6;
    const int m0 = blockIdx.y * BM;
    const int n0 = blockIdx.x * BN;
    constexpr int WM = BM / 2, WN = BN / 2, FM = WM / 16, FN = WN / 16;
    const int wm = (wave >> 1) * WM, wn = (wave & 1) * WN;
    const int lc = lane & 15, lg = lane >> 4;

    f32x4 acc[FM][FN] = {};

    constexpr int CA = BM * 8 / 256;
    constexpr int CB = BN * 8 / 256;

    for (int k0 = 0; k0 < K; k0 += BK) {
        #pragma unroll
        for (int j = 0; j < CA; ++j) {
            int ch = j * 256 + tid;
            int m = ch >> 3, kc = ch & 7;
            int mg = m0 + m; if (mg > M - 1) mg = M - 1;
            async16(&A[(size_t)mg * lda + k0 + kc * 8], &lA[ch * 8]);
        }
        #pragma unroll
        for (int j = 0; j < CB; ++j) {
            int ch = j * 256 + tid;
            int n = ch >> 3, kc = ch & 7;
            int ng = n0 + n; if (ng > N - 1) ng = N - 1;
            async16(&B[(size_t)ng * ldb + k0 + kc * 8], &lB[ch * 8]);
        }
        __syncthreads();
        #pragma unroll
        for (int ks = 0; ks < BK; ks += 32) {
            bf16x8 af[FM], bfr[FN];
            #pragma unroll
            for (int i = 0; i < FM; ++i)
                af[i] = *(const bf16x8*)&lA[(wm + i * 16 + lc) * BK + ks + lg * 8];
            #pragma unroll
            for (int j = 0; j < FN; ++j)
                bfr[j] = *(const bf16x8*)&lB[(wn + j * 16 + lc) * BK + ks + lg * 8];
            #pragma unroll
            for (int i = 0; i < FM; ++i)
                #pragma unroll
                for (int j = 0; j < FN; ++j)
                    acc[i][j] = mfma16(af[i], bfr[j], acc[i][j]);
        }
        __syncthreads();
    }

    #pragma unroll
    for (int i = 0; i < FM; ++i) {
        int rbase = m0 + wm + i * 16 + lg * 4;
        #pragma unroll
        for (int j = 0; j < FN; ++j) {
            int col = n0 + wn + j * 16 + lc;
            if (col >= N) continue;
            float bn = biasN ? (float)biasN[col] : 0.0f;
            #pragma unroll
            for (int r = 0; r < 4; ++r) {
                int row = rbase + r;
                if (row < M) {
                    float v = acc[i][j][r] + bn;
                    if (biasM) v += (float)biasM[row];
                    v *= csc;
                    size_t idx = cbase + (size_t)row * ldc + col;
                    if (outF32) ((float*)C)[idx] = v;
                    else ((__hip_bfloat16*)C)[idx] = __float2bfloat16(v);
                }
            }
        }
    }
}

// ---------------- flash attention v5: K=16 MFMA chaining (no P LDS round-trip)
// S^T = mfma16x16x16(A=K-frag, B=Q-frag): C regs (row=key=4lg+r, col=q=lc)
// are EXACTLY the B-operand layout (B[n=lc][k=4lg+j]) of the PV mfma:
// O^T = mfma16x16x16(A=Vt-frag, B=P-frag). exp2 + pack in registers between.
// q pre-scaled by log2(e)/64; fixed-max softmax; row-sum deferred (keys on lg
// -> 2 shuffles at end). K/V LDS-staged, XOR-swizzled, double-buffered.
// q,k: [H*B][S][64]; vT: [H*B][64][S]; out cT: [B][512][S] (combined^T)
__global__ __launch_bounds__(256, 2) void flash_attn(
    const __hip_bfloat16* __restrict__ q,
    const __hip_bfloat16* __restrict__ k,
    const __hip_bfloat16* __restrict__ vT,
    __hip_bfloat16* __restrict__ cT)
{
    const int S = 2048;
    const int h = blockIdx.y >> 2, b = blockIdx.y & 3;
    const int tid = threadIdx.x, lane = tid & 63, wave = tid >> 6;
    const int lc = lane & 15, lg = lane >> 4;
    const int s0 = blockIdx.x * 128 + wave * 32;

    const __hip_bfloat16* qb = q  + (size_t)(h * 4 + b) * S * 64;
    const __hip_bfloat16* kb = k  + (size_t)(h * 4 + b) * S * 64;
    const __hip_bfloat16* vb = vT + (size_t)(h * 4 + b) * 64 * S;

    // smem: staging lk[2][4096] @0, lv[2][4096] @8192 (32KB total);
    // epilogue overlays [0..8704) after final barrier.
    __shared__ __align__(16) __hip_bfloat16 smem[16384];
    __hip_bfloat16* lk = smem;
    __hip_bfloat16* lv = smem + 8192;

    // Q fragments: [f][c]: B[n=q=s0+f*16+lc][k(d) = c*16 + 4lg + j]
    short4v qf[2][4];
    #pragma unroll
    for (int f = 0; f < 2; ++f)
        #pragma unroll
        for (int c = 0; c < 4; ++c)
            qf[f][c] = *(const short4v*)&qb[(size_t)(s0 + f * 16 + lc) * 64 + c * 16 + lg * 4];

    // stage tile 0 (16B-chunk XOR swizzle)
    #pragma unroll
    for (int j = 0; j < 2; ++j) {
        int ch = j * 256 + tid;
        int row = ch >> 3, cg = (ch & 7) ^ (row & 7);
        async16(&kb[(size_t)row * 64 + cg * 8], &lk[ch * 8]);
        async16(&vb[(size_t)row * S  + cg * 8], &lv[ch * 8]);
    }
    __syncthreads();

    f32x4 O[2][4] = {};
    f32x4 lsum[2] = {};
    const int half8 = (lg & 1) * 4;   // 8B half within a 16B chunk

    for (int t = 0; t < 32; ++t) {
        const int cur = (t & 1) * 4096, nxt = cur ^ 4096;
        if (t + 1 < 32) {   // prefetch tile t+1 (drained at end-of-iter barrier)
            const int t1 = (t + 1) * 64;
            #pragma unroll
            for (int j = 0; j < 2; ++j) {
                int ch = j * 256 + tid;
                int row = ch >> 3, cg = (ch & 7) ^ (row & 7);
                async16(&kb[(size_t)(t1 + row) * 64 + cg * 8], &lk[nxt + ch * 8]);
                async16(&vb[(size_t)row * S + t1 + cg * 8],    &lv[nxt + ch * 8]);
            }
        }
        // S^T: per key-group kg (16 keys), chain 4 chunks of d
        f32x4 sc[2][4] = {};
        #pragma unroll
        for (int kg = 0; kg < 4; ++kg) {
            int row = kg * 16 + lc;
            #pragma unroll
            for (int c = 0; c < 4; ++c) {
                int pc = (2 * c + (lg >> 1)) ^ (row & 7);
                short4v kf = *(const short4v*)&lk[cur + row * 64 + pc * 8 + half8];
                sc[0][kg] = mfma16k(kf, qf[0][c], sc[0][kg]);
                sc[1][kg] = mfma16k(kf, qf[1][c], sc[1][kg]);
            }
        }
        // exp2, accumulate row-sum partials, pack to PV B-operands
        short4v pb[2][4];
        #pragma unroll
        for (int f = 0; f < 2; ++f)
            #pragma unroll
            for (int kg = 0; kg < 4; ++kg) {
                f32x4 e;
                #pragma unroll
                for (int r = 0; r < 4; ++r) e[r] = exp2f(sc[f][kg][r]);
                lsum[f] += e;
                pb[f][kg] = pack_bf16x4(e);
            }
        // O^T += Vt-frag x P-frag
        #pragma unroll
        for (int dt = 0; dt < 4; ++dt) {
            int row = dt * 16 + lc;
            #pragma unroll
            for (int kg = 0; kg < 4; ++kg) {
                int pc = (2 * kg + (lg >> 1)) ^ (row & 7);
                short4v vf = *(const short4v*)&lv[cur + row * 64 + pc * 8 + half8];
                O[0][dt] = mfma16k(vf, pb[0][kg], O[0][dt]);
                O[1][dt] = mfma16k(vf, pb[1][kg], O[1][dt]);
            }
        }
        __syncthreads();   // guards buffer swap + drains prefetch (overlapped)
    }
    // row-sum: per-lane partial covers keys 4lg+r (over kg,t); reduce over lg
    float inv[2];
    #pragma unroll
    for (int f = 0; f < 2; ++f) {
        float v = lsum[f][0] + lsum[f][1] + lsum[f][2] + lsum[f][3];
        v += __shfl_xor(v, 16);
        v += __shfl_xor(v, 32);
        inv[f] = 1.0f / v;   // each lane holds sum for its q=lc
    }
    // O^T frag: value(f,dt,r) = O[q=s0+f*16+lc][d=16dt+4lg+r]
    // -> smem[d][s_local] (stride 136), then coalesced b128 store
    #pragma unroll
    for (int f = 0; f < 2; ++f)
        #pragma unroll
        for (int dt = 0; dt < 4; ++dt)
            #pragma unroll
            for (int r = 0; r < 4; ++r)
                smem[(dt * 16 + lg * 4 + r) * 136 + wave * 32 + f * 16 + lc] =
                    __float2bfloat16(O[f][dt][r] * inv[f]);
    __syncthreads();
    int row = tid >> 2, c0 = (tid & 3) * 32;   // 64 d-rows x 128 s-cols
    size_t off = ((size_t)b * 512 + h * 64 + row) * S + blockIdx.x * 128 + c0;
    #pragma unroll
    for (int cc = 0; cc < 4; ++cc)
        *(bf16x8*)&cT[off + cc * 8] = *(const bf16x8*)&smem[row * 136 + c0 + cc * 8];
}

extern "C" void kernel_launch(void* const* d_in, const int* in_sizes, int n_in,
                              void* d_out, int out_size, void* d_ws, size_t ws_size,
                              hipStream_t stream) {
    using bf = __hip_bfloat16;
    bf* ws = (bf*)d_ws;
    int* flag = (int*)d_ws;
    bf* bqc = ws + 64;         // bqc/bkc contiguous (merged qk gemm bias)
    bf* bkc = ws + 576;
    bf* bvc = ws + 1088;
    bf* btc = ws + 1600;
    bf* boc = ws + 2320;
    bf* WqT = ws + 4096;       // [8][64][512]; WkT contiguous after
    bf* WkT = ws + 266240;
    bf* WvT = ws + 528384;
    bf* Wtc = ws + 790528;     // [720][2048]
    bf* Woc = ws + 2265088;    // [512][512]
    bf* Xc  = ws + 2527232;    // [4][2048][512], dead after QKV gemms
    bf* cT  = ws + 2527232;    // [4][512][2048], overlays Xc
    bf* q   = ws + 6721536;    // [32][2048][64]; kk contiguous after
    bf* up  = ws + 6721536;    // [4][720][512], overlays q after flash
    bf* kk  = ws + 10915840;   // [32][2048][64]
    bf* vT  = ws + 15110144;   // [32][64][2048]

    probe_dtype<<<dim3(1), 256, 0, stream>>>((const unsigned*)d_in[0], flag);

    CTab tab;
    tab.t[0]  = { d_in[0],  Xc,  4194304, 0 };
    tab.t[1]  = { d_in[1],  WqT, 262144,  1 };
    tab.t[2]  = { d_in[2],  bqc, 512,     0 };
    tab.t[3]  = { d_in[3],  WkT, 262144,  1 };
    tab.t[4]  = { d_in[4],  bkc, 512,     0 };
    tab.t[5]  = { d_in[5],  WvT, 262144,  1 };
    tab.t[6]  = { d_in[6],  bvc, 512,     0 };
    tab.t[7]  = { d_in[7],  Wtc, 1474560, 0 };
    tab.t[8]  = { d_in[8],  btc, 720,     0 };
    tab.t[9]  = { d_in[9],  Woc, 262144,  0 };
    tab.t[10] = { d_in[10], boc, 512,     0 };
    convert_all<<<dim3(2048, 11), 256, 0, stream>>>(tab, flag);

    // merged q+k: z1 0..7 -> q heads (scaled by log2(e)/64), z1 8..15 -> k heads
    const float qscale = 0.022542110013890054f;  // log2(e)/64
    gemm_bt<128, 64><<<dim3(1, 64, 16), 256, 0, stream>>>(
        Xc, WqT, q, 8192, 64, 512, 512, 512, 64,
        0, 0, 32768, 0, 524288, 0, nullptr, 0, bqc, 64, 1, nullptr, qscale, 8);

    // vT[h,b] = WvT[h] * Xc[b]^T + bv (per-row)  (z1=h, z0=b)
    gemm_bt<64, 128><<<dim3(16, 1, 32), 256, 0, stream>>>(
        WvT, Xc, vT, 64, 2048, 512, 512, 512, 2048,
        32768, 0, 0, 1048576, 524288, 131072, bvc, 64, nullptr, 0, 4, nullptr, 1.0f, 0);

    flash_attn<<<dim3(16, 32), 256, 0, stream>>>(q, kk, vT, cT);

    // up[b] = Wt * cT[b]^T + bt (per-row)   (z1 = b)
    gemm_bt<128, 64><<<dim3(8, 6, 4), 256, 0, stream>>>(
        Wtc, cT, up, 720, 512, 2048, 2048, 2048, 512,
        0, 0, 1048576, 0, 368640, 0, btc, 0, nullptr, 0, 1, nullptr, 1.0f, 0);

    // out = up * Woc^T + bo (per-col); dtype per probe flag
    gemm_bt<128, 64><<<dim3(8, 23, 1), 256, 0, stream>>>(
        up, Woc, d_out, 2880, 512, 512, 512, 512, 512,
        0, 0, 0, 0, 0, 0, nullptr, 0, boc, 0, 1, flag, 1.0f, 0);
}

// Round 10
// 236.348 us; speedup vs baseline: 1.8833x; 1.0689x over previous
//
#include <hip/hip_runtime.h>
#include <hip/hip_bf16.h>

// Model_3315714753203: B=4,S=2048,I=512,D=512,H=8,HD=64,P=720.
// fp32 inputs (probed) -> internal bf16. probe -> convert(+W transpose) ->
// GEMM qk(merged), vT -> flash attention v6 (QK via K=32 mfma w/ b128
// conflict-free K reads; S^T C-regs feed PV mfma16k B-operand directly;
// no P LDS round-trip) -> GEMM up -> GEMM out (64x64 tiles, 384/360 blocks).

typedef short bf16x8 __attribute__((ext_vector_type(8)));
typedef short short4v __attribute__((ext_vector_type(4)));
typedef float f32x4 __attribute__((ext_vector_type(4)));
typedef const __attribute__((address_space(1))) void* gptr_t;
typedef __attribute__((address_space(3))) void* sptr_t;

__device__ __forceinline__ f32x4 mfma16(bf16x8 a, bf16x8 b, f32x4 c) {
    return __builtin_amdgcn_mfma_f32_16x16x32_bf16(a, b, c, 0, 0, 0);
}
// K=16 bf16 MFMA. __has_builtin is target-dependent: 1 on the gfx950 device
// pass, 0 on host -> host gets a never-executed stub.
__device__ __forceinline__ f32x4 mfma16k(short4v a, short4v b, f32x4 c) {
#if __has_builtin(__builtin_amdgcn_mfma_f32_16x16x16bf16_1k)
    return __builtin_amdgcn_mfma_f32_16x16x16bf16_1k(a, b, c, 0, 0, 0);
#else
    (void)a; (void)b; return c;   // host-pass stub only
#endif
}
__device__ __forceinline__ void async16(const void* g, void* l) {
    __builtin_amdgcn_global_load_lds((gptr_t)g, (sptr_t)l, 16, 0, 0);
}
// pack 4 f32 -> 4 bf16 (round-half-up: +0x8000 then take high 16)
__device__ __forceinline__ short4v pack_bf16x4(f32x4 v) {
    unsigned a = __builtin_bit_cast(unsigned, v[0]) + 0x8000u;
    unsigned b = __builtin_bit_cast(unsigned, v[1]) + 0x8000u;
    unsigned c = __builtin_bit_cast(unsigned, v[2]) + 0x8000u;
    unsigned d = __builtin_bit_cast(unsigned, v[3]) + 0x8000u;
    int2 t;
    t.x = (int)__builtin_amdgcn_perm(b, a, 0x07060302u);
    t.y = (int)__builtin_amdgcn_perm(d, c, 0x07060302u);
    return __builtin_bit_cast(short4v, t);
}

// ---------------- dtype probe (decides fp32 vs bf16 decode at runtime)
__global__ void probe_dtype(const unsigned* __restrict__ x, int* __restrict__ flag) {
    __shared__ int cnt[256];
    int c = 0;
    for (int i = threadIdx.x; i < 1024; i += 256) {
        unsigned e = (x[i] >> 23) & 0xffu;
        c += (e >= 100u && e <= 145u) ? 1 : 0;
    }
    cnt[threadIdx.x] = c;
    __syncthreads();
    for (int s = 128; s > 0; s >>= 1) {
        if (threadIdx.x < s) cnt[threadIdx.x] += cnt[threadIdx.x + s];
        __syncthreads();
    }
    if (threadIdx.x == 0) *flag = (cnt[0] >= 512) ? 1 : 0;
}

// ---------------- convert all inputs to internal bf16 (mode1 = HID->HDI transpose)
struct CDesc { const void* s; __hip_bfloat16* d; int n; int mode; };
struct CTab  { CDesc t[11]; };

__global__ void convert_all(CTab tab, const int* __restrict__ flag) {
    CDesc de = tab.t[blockIdx.y];
    const int isF32 = *flag;
    for (int i = blockIdx.x * 256 + threadIdx.x; i < de.n; i += gridDim.x * 256) {
        int si = i;
        if (de.mode) {  // dst [h][d][i512]: i=(h*64+d)*512+ii  src [h][i512][d]
            int ii = i & 511, d = (i >> 9) & 63, h = i >> 15;
            si = (h * 512 + ii) * 64 + d;
        }
        float v = isF32 ? ((const float*)de.s)[si]
                        : (float)((const __hip_bfloat16*)de.s)[si];
        de.d[i] = __float2bfloat16(v);
    }
}

// ---------------- generic MFMA GEMM: C[M,N] = A[M,K]*B[N,K]^T + bias; *cscale if z1<scaleZmax
template<int BM, int BN>
__global__ __launch_bounds__(256, 2) void gemm_bt(
    const __hip_bfloat16* __restrict__ A,
    const __hip_bfloat16* __restrict__ B,
    void* __restrict__ C,
    int M, int N, int K, int lda, int ldb, int ldc,
    long sA1, long sA0, long sB1, long sB0, long sC1, long sC0,
    const __hip_bfloat16* __restrict__ biasM, long sbM1,
    const __hip_bfloat16* __restrict__ biasN, long sbN1,
    int Z0, const int* __restrict__ outF32flag, float cscale, int scaleZmax)
{
    constexpr int BK = 64;
    const int z = blockIdx.z;
    const int z1 = z / Z0, z0 = z - z1 * Z0;
    A += (size_t)z1 * sA1 + (size_t)z0 * sA0;
    B += (size_t)z1 * sB1 + (size_t)z0 * sB0;
    const size_t cbase = (size_t)z1 * sC1 + (size_t)z0 * sC0;
    if (biasM) biasM += (size_t)z1 * sbM1;
    if (biasN) biasN += (size_t)z1 * sbN1;
    const int outF32 = outF32flag ? *outF32flag : 0;
    const float csc = (z1 < scaleZmax) ? cscale : 1.0f;

    __shared__ __align__(16) __hip_bfloat16 lA[BM * BK];
    __shared__ __align__(16) __hip_bfloat16 lB[BN * BK];

    const int tid  = threadIdx.x;
    const int lane = tid & 63;
    const int wave = tid >> 6;
    const int m0 = blockIdx.y * BM;
    const int n0 = blockIdx.x * BN;
    constexpr int WM = BM / 2, WN = BN / 2, FM = WM / 16, FN = WN / 16;
    const int wm = (wave >> 1) * WM, wn = (wave & 1) * WN;
    const int lc = lane & 15, lg = lane >> 4;

    f32x4 acc[FM][FN] = {};

    constexpr int CA = BM * 8 / 256;
    constexpr int CB = BN * 8 / 256;

    for (int k0 = 0; k0 < K; k0 += BK) {
        #pragma unroll
        for (int j = 0; j < CA; ++j) {
            int ch = j * 256 + tid;
            int m = ch >> 3, kc = ch & 7;
            int mg = m0 + m; if (mg > M - 1) mg = M - 1;
            async16(&A[(size_t)mg * lda + k0 + kc * 8], &lA[ch * 8]);
        }
        #pragma unroll
        for (int j = 0; j < CB; ++j) {
            int ch = j * 256 + tid;
            int n = ch >> 3, kc = ch & 7;
            int ng = n0 + n; if (ng > N - 1) ng = N - 1;
            async16(&B[(size_t)ng * ldb + k0 + kc * 8], &lB[ch * 8]);
        }
        __syncthreads();
        #pragma unroll
        for (int ks = 0; ks < BK; ks += 32) {
            bf16x8 af[FM], bfr[FN];
            #pragma unroll
            for (int i = 0; i < FM; ++i)
                af[i] = *(const bf16x8*)&lA[(wm + i * 16 + lc) * BK + ks + lg * 8];
            #pragma unroll
            for (int j = 0; j < FN; ++j)
                bfr[j] = *(const bf16x8*)&lB[(wn + j * 16 + lc) * BK + ks + lg * 8];
            #pragma unroll
            for (int i = 0; i < FM; ++i)
                #pragma unroll
                for (int j = 0; j < FN; ++j)
                    acc[i][j] = mfma16(af[i], bfr[j], acc[i][j]);
        }
        __syncthreads();
    }

    #pragma unroll
    for (int i = 0; i < FM; ++i) {
        int rbase = m0 + wm + i * 16 + lg * 4;
        #pragma unroll
        for (int j = 0; j < FN; ++j) {
            int col = n0 + wn + j * 16 + lc;
            if (col >= N) continue;
            float bn = biasN ? (float)biasN[col] : 0.0f;
            #pragma unroll
            for (int r = 0; r < 4; ++r) {
                int row = rbase + r;
                if (row < M) {
                    float v = acc[i][j][r] + bn;
                    if (biasM) v += (float)biasM[row];
                    v *= csc;
                    size_t idx = cbase + (size_t)row * ldc + col;
                    if (outF32) ((float*)C)[idx] = v;
                    else ((__hip_bfloat16*)C)[idx] = __float2bfloat16(v);
                }
            }
        }
    }
}

// ---------------- flash attention v6
// QK^T via mfma 16x16x32: A = K rows (b128 LDS reads, chunk=lg^(row&7),
// conflict-free — r9's b64 reads were 4-way conflicted, 8.4M cy), B = Q
// (global bf16x8). C-layout of 16x16x32 == 16x16x16 => S^T regs
// [key=4lg+r][q=lc] still feed PV mfma16k B-operand directly (no LDS).
// q pre-scaled by log2(e)/64; fixed-max softmax; row-sum deferred.
// q,k: [H*B][S][64]; vT: [H*B][64][S]; out cT: [B][512][S] (combined^T)
__global__ __launch_bounds__(256, 2) void flash_attn(
    const __hip_bfloat16* __restrict__ q,
    const __hip_bfloat16* __restrict__ k,
    const __hip_bfloat16* __restrict__ vT,
    __hip_bfloat16* __restrict__ cT)
{
    const int S = 2048;
    const int h = blockIdx.y >> 2, b = blockIdx.y & 3;
    const int tid = threadIdx.x, lane = tid & 63, wave = tid >> 6;
    const int lc = lane & 15, lg = lane >> 4;
    const int s0 = blockIdx.x * 128 + wave * 32;

    const __hip_bfloat16* qb = q  + (size_t)(h * 4 + b) * S * 64;
    const __hip_bfloat16* kb = k  + (size_t)(h * 4 + b) * S * 64;
    const __hip_bfloat16* vb = vT + (size_t)(h * 4 + b) * 64 * S;

    __shared__ __align__(16) __hip_bfloat16 smem[16384];
    __hip_bfloat16* lk = smem;
    __hip_bfloat16* lv = smem + 8192;

    // Q as K=32 B-operand: [f][half]: B[n=q=s0+f*16+lc][k(d)=half*32+8lg+j]
    bf16x8 qf[2][2];
    #pragma unroll
    for (int f = 0; f < 2; ++f)
        #pragma unroll
        for (int hh = 0; hh < 2; ++hh)
            qf[f][hh] = *(const bf16x8*)&qb[(size_t)(s0 + f * 16 + lc) * 64 + hh * 32 + lg * 8];

    // stage tile 0 (16B-chunk XOR swizzle)
    #pragma unroll
    for (int j = 0; j < 2; ++j) {
        int ch = j * 256 + tid;
        int row = ch >> 3, cg = (ch & 7) ^ (row & 7);
        async16(&kb[(size_t)row * 64 + cg * 8], &lk[ch * 8]);
        async16(&vb[(size_t)row * S  + cg * 8], &lv[ch * 8]);
    }
    __syncthreads();

    f32x4 O[2][4] = {};
    f32x4 lsum[2] = {};
    const int half8 = (lg & 1) * 4;   // 8B half within a 16B chunk (V reads)

    for (int t = 0; t < 32; ++t) {
        const int cur = (t & 1) * 4096, nxt = cur ^ 4096;
        if (t + 1 < 32) {   // prefetch tile t+1 (drained at end-of-iter barrier)
            const int t1 = (t + 1) * 64;
            #pragma unroll
            for (int j = 0; j < 2; ++j) {
                int ch = j * 256 + tid;
                int row = ch >> 3, cg = (ch & 7) ^ (row & 7);
                async16(&kb[(size_t)(t1 + row) * 64 + cg * 8], &lk[nxt + ch * 8]);
                async16(&vb[(size_t)row * S + t1 + cg * 8],    &lv[nxt + ch * 8]);
            }
        }
        // S^T: K=32 mfma, A = K rows (b128, conflict-free), B = Q regs
        f32x4 sc[2][4] = {};
        #pragma unroll
        for (int kg = 0; kg < 4; ++kg) {
            int row = kg * 16 + lc, sw = row & 7;
            bf16x8 kf0 = *(const bf16x8*)&lk[cur + row * 64 + ((0 + lg) ^ sw) * 8];
            bf16x8 kf1 = *(const bf16x8*)&lk[cur + row * 64 + ((4 + lg) ^ sw) * 8];
            #pragma unroll
            for (int f = 0; f < 2; ++f) {
                sc[f][kg] = mfma16(kf0, qf[f][0], sc[f][kg]);
                sc[f][kg] = mfma16(kf1, qf[f][1], sc[f][kg]);
            }
        }
        // exp2, accumulate row-sum partials, pack to PV B-operands
        short4v pb[2][4];
        #pragma unroll
        for (int f = 0; f < 2; ++f)
            #pragma unroll
            for (int kg = 0; kg < 4; ++kg) {
                f32x4 e;
                #pragma unroll
                for (int r = 0; r < 4; ++r) e[r] = exp2f(sc[f][kg][r]);
                lsum[f] += e;
                pb[f][kg] = pack_bf16x4(e);
            }
        // O^T += Vt-frag x P-frag (mfma16k; V b64 reads)
        #pragma unroll
        for (int dt = 0; dt < 4; ++dt) {
            int row = dt * 16 + lc;
            #pragma unroll
            for (int kg = 0; kg < 4; ++kg) {
                int pc = (2 * kg + (lg >> 1)) ^ (row & 7);
                short4v vf = *(const short4v*)&lv[cur + row * 64 + pc * 8 + half8];
                O[0][dt] = mfma16k(vf, pb[0][kg], O[0][dt]);
                O[1][dt] = mfma16k(vf, pb[1][kg], O[1][dt]);
            }
        }
        __syncthreads();   // guards buffer swap + drains prefetch (overlapped)
    }
    // row-sum: per-lane partial covers keys 4lg+r (over kg,t); reduce over lg
    float inv[2];
    #pragma unroll
    for (int f = 0; f < 2; ++f) {
        float v = lsum[f][0] + lsum[f][1] + lsum[f][2] + lsum[f][3];
        v += __shfl_xor(v, 16);
        v += __shfl_xor(v, 32);
        inv[f] = 1.0f / v;   // each lane holds sum for its q=lc
    }
    // O^T frag: value(f,dt,r) = O[q=s0+f*16+lc][d=16dt+4lg+r]
    // -> smem[d][s_local] (stride 136), then coalesced b128 store
    #pragma unroll
    for (int f = 0; f < 2; ++f)
        #pragma unroll
        for (int dt = 0; dt < 4; ++dt)
            #pragma unroll
            for (int r = 0; r < 4; ++r)
                smem[(dt * 16 + lg * 4 + r) * 136 + wave * 32 + f * 16 + lc] =
                    __float2bfloat16(O[f][dt][r] * inv[f]);
    __syncthreads();
    int row = tid >> 2, c0 = (tid & 3) * 32;   // 64 d-rows x 128 s-cols
    size_t off = ((size_t)b * 512 + h * 64 + row) * S + blockIdx.x * 128 + c0;
    #pragma unroll
    for (int cc = 0; cc < 4; ++cc)
        *(bf16x8*)&cT[off + cc * 8] = *(const bf16x8*)&smem[row * 136 + c0 + cc * 8];
}

extern "C" void kernel_launch(void* const* d_in, const int* in_sizes, int n_in,
                              void* d_out, int out_size, void* d_ws, size_t ws_size,
                              hipStream_t stream) {
    using bf = __hip_bfloat16;
    bf* ws = (bf*)d_ws;
    int* flag = (int*)d_ws;
    bf* bqc = ws + 64;         // bqc/bkc contiguous (merged qk gemm bias)
    bf* bkc = ws + 576;
    bf* bvc = ws + 1088;
    bf* btc = ws + 1600;
    bf* boc = ws + 2320;
    bf* WqT = ws + 4096;       // [8][64][512]; WkT contiguous after
    bf* WkT = ws + 266240;
    bf* WvT = ws + 528384;
    bf* Wtc = ws + 790528;     // [720][2048]
    bf* Woc = ws + 2265088;    // [512][512]
    bf* Xc  = ws + 2527232;    // [4][2048][512], dead after QKV gemms
    bf* cT  = ws + 2527232;    // [4][512][2048], overlays Xc
    bf* q   = ws + 6721536;    // [32][2048][64]; kk contiguous after
    bf* up  = ws + 6721536;    // [4][720][512], overlays q after flash
    bf* kk  = ws + 10915840;   // [32][2048][64]
    bf* vT  = ws + 15110144;   // [32][64][2048]

    probe_dtype<<<dim3(1), 256, 0, stream>>>((const unsigned*)d_in[0], flag);

    CTab tab;
    tab.t[0]  = { d_in[0],  Xc,  4194304, 0 };
    tab.t[1]  = { d_in[1],  WqT, 262144,  1 };
    tab.t[2]  = { d_in[2],  bqc, 512,     0 };
    tab.t[3]  = { d_in[3],  WkT, 262144,  1 };
    tab.t[4]  = { d_in[4],  bkc, 512,     0 };
    tab.t[5]  = { d_in[5],  WvT, 262144,  1 };
    tab.t[6]  = { d_in[6],  bvc, 512,     0 };
    tab.t[7]  = { d_in[7],  Wtc, 1474560, 0 };
    tab.t[8]  = { d_in[8],  btc, 720,     0 };
    tab.t[9]  = { d_in[9],  Woc, 262144,  0 };
    tab.t[10] = { d_in[10], boc, 512,     0 };
    convert_all<<<dim3(2048, 11), 256, 0, stream>>>(tab, flag);

    // merged q+k: z1 0..7 -> q heads (scaled by log2(e)/64), z1 8..15 -> k heads
    const float qscale = 0.022542110013890054f;  // log2(e)/64
    gemm_bt<128, 64><<<dim3(1, 64, 16), 256, 0, stream>>>(
        Xc, WqT, q, 8192, 64, 512, 512, 512, 64,
        0, 0, 32768, 0, 524288, 0, nullptr, 0, bqc, 64, 1, nullptr, qscale, 8);

    // vT[h,b] = WvT[h] * Xc[b]^T + bv (per-row)  (z1=h, z0=b)
    gemm_bt<64, 128><<<dim3(16, 1, 32), 256, 0, stream>>>(
        WvT, Xc, vT, 64, 2048, 512, 512, 512, 2048,
        32768, 0, 0, 1048576, 524288, 131072, bvc, 64, nullptr, 0, 4, nullptr, 1.0f, 0);

    flash_attn<<<dim3(16, 32), 256, 0, stream>>>(q, kk, vT, cT);

    // up[b] = Wt * cT[b]^T + bt (per-row)  (z1=b); 64x64 tiles -> 384 blocks
    gemm_bt<64, 64><<<dim3(8, 12, 4), 256, 0, stream>>>(
        Wtc, cT, up, 720, 512, 2048, 2048, 2048, 512,
        0, 0, 1048576, 0, 368640, 0, btc, 0, nullptr, 0, 1, nullptr, 1.0f, 0);

    // out = up * Woc^T + bo (per-col); dtype per probe flag; 360 blocks
    gemm_bt<64, 64><<<dim3(8, 45, 1), 256, 0, stream>>>(
        up, Woc, d_out, 2880, 512, 512, 512, 512, 512,
        0, 0, 0, 0, 0, 0, nullptr, 0, boc, 0, 1, flag, 1.0f, 0);
}